// Round 1
// baseline (1151.628 us; speedup 1.0000x reference)
//
#include <hip/hip_runtime.h>
#include <math.h>

#define BB 32
#define HH 16
#define DD 256
#define RDIM 64
#define NEMB 4096
#define NINT 16384
#define NSLOTS 32768
#define KVLEN 1024
#define LNEPS 1e-5f

// ---------------- LayerNorm -> hT [NE][B] (transposed for GEMM A) ----------------
__global__ __launch_bounds__(256) void ln_kernel(const float* __restrict__ x,
    const float* __restrict__ lw, const float* __restrict__ lb,
    float* __restrict__ hT)
{
    int b = blockIdx.x;
    int t = threadIdx.x;
    const float* row = x + (size_t)b * NEMB;
    float4 v[4];
    float sum = 0.f, sq = 0.f;
#pragma unroll
    for (int j = 0; j < 4; ++j) {
        v[j] = *(const float4*)(row + t * 4 + j * 1024);
        sum += v[j].x + v[j].y + v[j].z + v[j].w;
        sq += v[j].x * v[j].x + v[j].y * v[j].y + v[j].z * v[j].z + v[j].w * v[j].w;
    }
    __shared__ float s1[4], s2[4];
#pragma unroll
    for (int o = 32; o > 0; o >>= 1) {
        sum += __shfl_xor(sum, o, 64);
        sq += __shfl_xor(sq, o, 64);
    }
    int wave = t >> 6, lane = t & 63;
    if (lane == 0) { s1[wave] = sum; s2[wave] = sq; }
    __syncthreads();
    sum = s1[0] + s1[1] + s1[2] + s1[3];
    sq = s2[0] + s2[1] + s2[2] + s2[3];
    float mu = sum / NEMB;
    float var = sq / NEMB - mu * mu;
    float rstd = rsqrtf(var + LNEPS);
#pragma unroll
    for (int j = 0; j < 4; ++j) {
        int n = t * 4 + j * 1024;
        float4 wv = *(const float4*)(lw + n);
        float4 bv = *(const float4*)(lb + n);
        hT[(size_t)(n + 0) * BB + b] = (v[j].x - mu) * rstd * wv.x + bv.x;
        hT[(size_t)(n + 1) * BB + b] = (v[j].y - mu) * rstd * wv.y + bv.y;
        hT[(size_t)(n + 2) * BB + b] = (v[j].z - mu) * rstd * wv.z + bv.z;
        hT[(size_t)(n + 3) * BB + b] = (v[j].w - mu) * rstd * wv.w + bv.w;
    }
}

// ---------------- Skinny GEMM: P[z][s][n][32] partials; A transposed [K][32] ----------------
__global__ __launch_bounds__(256) void gemm_p_kernel(const float* __restrict__ AT,
    const float* __restrict__ W0, const float* __restrict__ W1, const float* __restrict__ W2,
    float* __restrict__ P, int N, int kChunk)
{
    const float* W = W0;
    if (blockIdx.z == 1) W = W1;
    else if (blockIdx.z == 2) W = W2;
    int n = blockIdx.x * 256 + threadIdx.x;
    int s = blockIdx.y;
    int S = gridDim.y;
    size_t k0 = (size_t)s * kChunk;
    float acc[32];
#pragma unroll
    for (int m = 0; m < 32; ++m) acc[m] = 0.f;
    const float* w = W + k0 * N + n;
    const float* a = AT + k0 * 32;   // wave-uniform, contiguous 128B per k
    for (int kk = 0; kk < kChunk; ++kk) {
        float wv = *w;
#pragma unroll
        for (int m = 0; m < 32; ++m) acc[m] = fmaf(a[m], wv, acc[m]);
        w += N;
        a += 32;
    }
    float* p = P + (((size_t)blockIdx.z * S + s) * N + n) * 32;
#pragma unroll
    for (int m = 0; m < 32; m += 4)
        *(float4*)(p + m) = make_float4(acc[m], acc[m + 1], acc[m + 2], acc[m + 3]);
}

__device__ inline float gelu_tanh(float x)
{
    float x3 = x * x * x;
    return 0.5f * x * (1.f + tanhf(0.7978845608028654f * (x + 0.044715f * x3)));
}

// MODE 0: plain row-major out[m][N]
// MODE 1: gelu(v+bias), transposed out[n][32]
// MODE 2: v + bias + add0[m][N] + add1[m][N] -> out[m][N]
template<int MODE>
__global__ __launch_bounds__(256) void reduce_kernel(
    const float* __restrict__ P, int S, int N,
    const float* __restrict__ bias, const float* __restrict__ add0,
    const float* __restrict__ add1, float* __restrict__ out)
{
    int n = blockIdx.x * 256 + threadIdx.x;
    int mq = blockIdx.y;  // m range mq*8 .. mq*8+7
    float v[8];
#pragma unroll
    for (int j = 0; j < 8; ++j) v[j] = 0.f;
    const float* p = P + (size_t)n * 32 + mq * 8;
    for (int s = 0; s < S; ++s) {
#pragma unroll
        for (int j = 0; j < 8; j += 4) {
            float4 u = *(const float4*)(p + j);
            v[j] += u.x; v[j + 1] += u.y; v[j + 2] += u.z; v[j + 3] += u.w;
        }
        p += (size_t)N * 32;
    }
    if (MODE == 0) {
#pragma unroll
        for (int j = 0; j < 8; ++j) out[(size_t)(mq * 8 + j) * N + n] = v[j];
    } else if (MODE == 1) {
        float bn = bias[n];
#pragma unroll
        for (int j = 0; j < 8; ++j) v[j] = gelu_tanh(v[j] + bn);
        float* o = out + (size_t)n * 32 + mq * 8;
        *(float4*)(o) = make_float4(v[0], v[1], v[2], v[3]);
        *(float4*)(o + 4) = make_float4(v[4], v[5], v[6], v[7]);
    } else {
        float bn = bias[n];
#pragma unroll
        for (int j = 0; j < 8; ++j) {
            int m = mq * 8 + j;
            out[(size_t)m * N + n] = v[j] + bn + add0[(size_t)m * N + n] + add1[(size_t)m * N + n];
        }
    }
}

// ---------------- RoPE in place on q and k (row-major [B][NE]) ----------------
__global__ void rope_kernel(float* __restrict__ q, float* __restrict__ k,
    const int* __restrict__ pos_ids)
{
    int b = blockIdx.x;
    int t = threadIdx.x;          // 0..511
    int h = t >> 5, i = t & 31;   // i = rotary pair index
    float pos = (float)pos_ids[b];
    float freq = powf(10000.f, -(float)(2 * i) / (float)RDIM);
    float ang = pos * freq;
    float sn, cs;
    sincosf(ang, &sn, &cs);
    size_t base = (size_t)b * NEMB + (size_t)h * DD + 2 * i;
    float q1 = q[base], q2 = q[base + 1];
    q[base] = q1 * cs - q2 * sn;
    q[base + 1] = q2 * cs + q1 * sn;
    float k1 = k[base], k2 = k[base + 1];
    k[base] = k1 * cs - k2 * sn;
    k[base + 1] = k2 * cs + k1 * sn;
}

// ---------------- cache-override maps ----------------
__global__ void ov_init_kernel(int* __restrict__ ovk, int* __restrict__ ovv)
{
    int i = blockIdx.x * 256 + threadIdx.x;
    if (i < NSLOTS) { ovk[i] = -1; ovv[i] = -1; }
}
__global__ void ov_scatter_kernel(int* __restrict__ ovk, int* __restrict__ ovv,
    const int* __restrict__ nkl, const int* __restrict__ nvl)
{
    int j = threadIdx.x;
    if (j < BB) {
        atomicMax(&ovk[nkl[j]], j);
        atomicMax(&ovv[nvl[j]], j);
    }
}

// ---------------- attention: one block per (b,h) ----------------
__global__ __launch_bounds__(256) void attn_kernel(const float* __restrict__ q,
    const float* __restrict__ knew, const float* __restrict__ vnew,
    const float* __restrict__ kcache, const float* __restrict__ vcache,
    const int* __restrict__ kidx, const int* __restrict__ vidx,
    const int* __restrict__ ovk, const int* __restrict__ ovv,
    const float* __restrict__ mask, float* __restrict__ ctxT)
{
    int bh = blockIdx.x;
    int b = bh >> 4, h = bh & 15;
    int t = threadIdx.x;
    __shared__ float qs[DD];
    __shared__ float sc[KVLEN];
    __shared__ const float* kp[KVLEN];
    __shared__ const float* vp[KVLEN];
    __shared__ float red[4];

    qs[t] = q[(size_t)b * NEMB + (size_t)h * DD + t];
#pragma unroll
    for (int j = 0; j < 4; ++j) {
        int l = t + j * 256;
        int ks = kidx[b * KVLEN + l];
        int vs = vidx[b * KVLEN + l];
        int ok = ovk[ks], ov = ovv[vs];
        kp[l] = (ok >= 0) ? (knew + (size_t)ok * NEMB + (size_t)h * DD)
                          : (kcache + (size_t)ks * NEMB + (size_t)h * DD);
        vp[l] = (ov >= 0) ? (vnew + (size_t)ov * NEMB + (size_t)h * DD)
                          : (vcache + (size_t)vs * NEMB + (size_t)h * DD);
    }
    __syncthreads();

    int wave = t >> 6, lane = t & 63;
    float4 qf = *(const float4*)(qs + lane * 4);
    for (int l = wave; l < KVLEN; l += 4) {
        const float4 kf = *(const float4*)(kp[l] + lane * 4);
        float d = kf.x * qf.x + kf.y * qf.y + kf.z * qf.z + kf.w * qf.w;
#pragma unroll
        for (int o = 32; o > 0; o >>= 1) d += __shfl_xor(d, o, 64);
        if (lane == 0) sc[l] = d * 0.0625f + mask[b * KVLEN + l];
    }
    __syncthreads();

    // softmax over 1024 in LDS
    float mx = -INFINITY;
#pragma unroll
    for (int j = 0; j < 4; ++j) mx = fmaxf(mx, sc[t + j * 256]);
#pragma unroll
    for (int o = 32; o > 0; o >>= 1) mx = fmaxf(mx, __shfl_xor(mx, o, 64));
    if (lane == 0) red[wave] = mx;
    __syncthreads();
    float bmax = fmaxf(fmaxf(red[0], red[1]), fmaxf(red[2], red[3]));
    float e[4];
    float sum = 0.f;
#pragma unroll
    for (int j = 0; j < 4; ++j) {
        e[j] = expf(sc[t + j * 256] - bmax);
        sum += e[j];
    }
#pragma unroll
    for (int o = 32; o > 0; o >>= 1) sum += __shfl_xor(sum, o, 64);
    __syncthreads();
    if (lane == 0) red[wave] = sum;
    __syncthreads();
    float inv = 1.f / (red[0] + red[1] + red[2] + red[3]);
#pragma unroll
    for (int j = 0; j < 4; ++j) sc[t + j * 256] = e[j] * inv;
    __syncthreads();

    // ctx: thread t owns dim t
    float acc = 0.f;
#pragma unroll 8
    for (int l = 0; l < KVLEN; ++l) {
        acc = fmaf(sc[l], vp[l][t], acc);
    }
    ctxT[((size_t)h * DD + t) * BB + b] = acc;
}

extern "C" void kernel_launch(void* const* d_in, const int* in_sizes, int n_in,
                              void* d_out, int out_size, void* d_ws, size_t ws_size,
                              hipStream_t stream)
{
    (void)in_sizes; (void)n_in; (void)out_size; (void)ws_size;
    const float* hs      = (const float*)d_in[0];
    const float* kcache  = (const float*)d_in[1];
    const float* vcache  = (const float*)d_in[2];
    const float* ln_w    = (const float*)d_in[3];
    const float* ln_b    = (const float*)d_in[4];
    const float* wq      = (const float*)d_in[5];
    const float* wk      = (const float*)d_in[6];
    const float* wv      = (const float*)d_in[7];
    const float* wo      = (const float*)d_in[8];
    const float* fc_in_w = (const float*)d_in[9];
    const float* fc_in_b = (const float*)d_in[10];
    const float* fc_out_w= (const float*)d_in[11];
    const float* fc_out_b= (const float*)d_in[12];
    const float* mask    = (const float*)d_in[13];
    const int* nkl       = (const int*)d_in[14];
    const int* nvl       = (const int*)d_in[15];
    const int* kidx      = (const int*)d_in[16];
    const int* vidx      = (const int*)d_in[17];
    const int* pos       = (const int*)d_in[18];
    float* out = (float*)d_out;

    char* ws = (char*)d_ws;
    float* hT      = (float*)ws; ws += (size_t)NEMB * BB * 4;      // 512K
    float* qb      = (float*)ws; ws += (size_t)BB * NEMB * 4;      // 512K
    float* kb      = (float*)ws; ws += (size_t)BB * NEMB * 4;      // 512K
    float* vb      = (float*)ws; ws += (size_t)BB * NEMB * 4;      // 512K
    float* ctxT    = (float*)ws; ws += (size_t)NEMB * BB * 4;      // 512K
    float* attn_o  = (float*)ws; ws += (size_t)BB * NEMB * 4;      // 512K
    float* mT      = (float*)ws; ws += (size_t)NINT * BB * 4;      // 2M
    int*   ovk     = (int*)ws;   ws += (size_t)NSLOTS * 4;         // 128K
    int*   ovv     = (int*)ws;   ws += (size_t)NSLOTS * 4;         // 128K
    float* P       = (float*)ws;                                   // up to 24M

    ln_kernel<<<BB, 256, 0, stream>>>(hs, ln_w, ln_b, hT);
    ov_init_kernel<<<NSLOTS / 256, 256, 0, stream>>>(ovk, ovv);
    ov_scatter_kernel<<<1, 64, 0, stream>>>(ovk, ovv, nkl, nvl);

    // QKV: N=4096, K=4096, S=16 (chunk 256), z selects weight
    gemm_p_kernel<<<dim3(16, 16, 3), 256, 0, stream>>>(hT, wq, wk, wv, P, NEMB, NEMB / 16);
    size_t psl = (size_t)16 * NEMB * 32;
    reduce_kernel<0><<<dim3(16, 4), 256, 0, stream>>>(P,           16, NEMB, nullptr, nullptr, nullptr, qb);
    reduce_kernel<0><<<dim3(16, 4), 256, 0, stream>>>(P + psl,     16, NEMB, nullptr, nullptr, nullptr, kb);
    reduce_kernel<0><<<dim3(16, 4), 256, 0, stream>>>(P + 2 * psl, 16, NEMB, nullptr, nullptr, nullptr, vb);

    rope_kernel<<<BB, 512, 0, stream>>>(qb, kb, pos);

    attn_kernel<<<BB * HH, 256, 0, stream>>>(qb, kb, vb, kcache, vcache,
                                             kidx, vidx, ovk, ovv, mask, ctxT);

    // Wo: A=ctxT, N=4096, K=4096, S=16
    gemm_p_kernel<<<dim3(16, 16, 1), 256, 0, stream>>>(ctxT, wo, wo, wo, P, NEMB, NEMB / 16);
    reduce_kernel<0><<<dim3(16, 4), 256, 0, stream>>>(P, 16, NEMB, nullptr, nullptr, nullptr, attn_o);

    // fc_in: A=hT, N=16384, K=4096, S=8 (chunk 512) -> gelu -> mT [NI][32]
    gemm_p_kernel<<<dim3(64, 8, 1), 256, 0, stream>>>(hT, fc_in_w, fc_in_w, fc_in_w, P, NINT, NEMB / 8);
    reduce_kernel<1><<<dim3(64, 4), 256, 0, stream>>>(P, 8, NINT, fc_in_b, nullptr, nullptr, mT);

    // fc_out: A=mT, N=4096, K=16384, S=32 (chunk 512); fused final add
    gemm_p_kernel<<<dim3(16, 32, 1), 256, 0, stream>>>(mT, fc_out_w, fc_out_w, fc_out_w, P, NEMB, NINT / 32);
    reduce_kernel<2><<<dim3(16, 4), 256, 0, stream>>>(P, 32, NEMB, fc_out_b, attn_o, hs, out);
}

// Round 2
// 681.244 us; speedup vs baseline: 1.6905x; 1.6905x over previous
//
#include <hip/hip_runtime.h>
#include <math.h>

#define BB 32
#define HH 16
#define DD 256
#define RDIM 64
#define NEMB 4096
#define NINT 16384
#define NSLOTS 32768
#define KVLEN 1024
#define LNEPS 1e-5f
#define NCH 8
#define CH 128

// ---------------- LayerNorm -> hT [NE][32] (A-transposed for GEMM) ----------------
__global__ __launch_bounds__(256) void ln_kernel(const float* __restrict__ x,
    const float* __restrict__ lw, const float* __restrict__ lb,
    float* __restrict__ hT)
{
    int b = blockIdx.x;
    int t = threadIdx.x;
    const float* row = x + (size_t)b * NEMB;
    float4 v[4];
    float sum = 0.f, sq = 0.f;
#pragma unroll
    for (int j = 0; j < 4; ++j) {
        v[j] = *(const float4*)(row + t * 4 + j * 1024);
        sum += v[j].x + v[j].y + v[j].z + v[j].w;
        sq += v[j].x * v[j].x + v[j].y * v[j].y + v[j].z * v[j].z + v[j].w * v[j].w;
    }
    __shared__ float s1[4], s2[4];
#pragma unroll
    for (int o = 32; o > 0; o >>= 1) {
        sum += __shfl_xor(sum, o, 64);
        sq += __shfl_xor(sq, o, 64);
    }
    int wave = t >> 6, lane = t & 63;
    if (lane == 0) { s1[wave] = sum; s2[wave] = sq; }
    __syncthreads();
    sum = s1[0] + s1[1] + s1[2] + s1[3];
    sq = s2[0] + s2[1] + s2[2] + s2[3];
    float mu = sum / NEMB;
    float var = sq / NEMB - mu * mu;
    float rstd = rsqrtf(var + LNEPS);
#pragma unroll
    for (int j = 0; j < 4; ++j) {
        int n = t * 4 + j * 1024;
        float4 wv = *(const float4*)(lw + n);
        float4 bv = *(const float4*)(lb + n);
        hT[(size_t)(n + 0) * BB + b] = (v[j].x - mu) * rstd * wv.x + bv.x;
        hT[(size_t)(n + 1) * BB + b] = (v[j].y - mu) * rstd * wv.y + bv.y;
        hT[(size_t)(n + 2) * BB + b] = (v[j].z - mu) * rstd * wv.z + bv.z;
        hT[(size_t)(n + 3) * BB + b] = (v[j].w - mu) * rstd * wv.w + bv.w;
    }
}

// ---------------- Skinny GEMM: thread = 4n x 16m; P[(s*32+m)*N + n] ----------------
// grid: x = N/1024, y = S (k-chunks), z = widx*2 + mhalf
__global__ __launch_bounds__(256) void gemm16_kernel(const float* __restrict__ AT,
    const float* __restrict__ W0, const float* __restrict__ W1, const float* __restrict__ W2,
    float* __restrict__ P, int N, int kChunk)
{
    int z = blockIdx.z;
    int widx = z >> 1, mh = (z & 1) * 16;
    const float* W = W0;
    if (widx == 1) W = W1;
    else if (widx == 2) W = W2;
    int n = (blockIdx.x * 256 + threadIdx.x) * 4;
    int s = blockIdx.y, S = gridDim.y;
    size_t k0 = (size_t)s * kChunk;
    float4 acc[16];
#pragma unroll
    for (int mi = 0; mi < 16; ++mi) acc[mi] = make_float4(0.f, 0.f, 0.f, 0.f);
    const float* w = W + k0 * N + n;
    const float* a = AT + k0 * 32 + mh;   // wave-uniform
#pragma unroll 4
    for (int kk = 0; kk < kChunk; ++kk) {
        float4 wv = *(const float4*)w;
#pragma unroll
        for (int mi = 0; mi < 16; ++mi) {
            float am = a[mi];
            acc[mi].x = fmaf(am, wv.x, acc[mi].x);
            acc[mi].y = fmaf(am, wv.y, acc[mi].y);
            acc[mi].z = fmaf(am, wv.z, acc[mi].z);
            acc[mi].w = fmaf(am, wv.w, acc[mi].w);
        }
        w += N;
        a += 32;
    }
    float* p = P + (size_t)widx * ((size_t)S * 32 * N) + ((size_t)(s * 32 + mh) * N) + n;
#pragma unroll
    for (int mi = 0; mi < 16; ++mi)
        *(float4*)(p + (size_t)mi * N) = acc[mi];
}

__device__ inline float gelu_tanh(float x)
{
    float x3 = x * x * x;
    return 0.5f * x * (1.f + tanhf(0.7978845608028654f * (x + 0.044715f * x3)));
}

// MODE 0: out[m][N]   MODE 1: gelu(v+bias) -> out[n][32]   MODE 2: v+bias+add0+add1 -> out[m][N]
// grid: (N/256, 32); thread = one (n, m)
template<int MODE>
__global__ __launch_bounds__(256) void reduce2_kernel(
    const float* __restrict__ P, int S, int N,
    const float* __restrict__ bias, const float* __restrict__ add0,
    const float* __restrict__ add1, float* __restrict__ out)
{
    int n = blockIdx.x * 256 + threadIdx.x;
    int m = blockIdx.y;
    float v = 0.f;
    const float* p = P + (size_t)m * N + n;
#pragma unroll 4
    for (int s = 0; s < S; ++s) {
        v += *p;
        p += (size_t)32 * N;
    }
    if (MODE == 0) {
        out[(size_t)m * N + n] = v;
    } else if (MODE == 1) {
        out[(size_t)n * 32 + m] = gelu_tanh(v + bias[n]);
    } else {
        out[(size_t)m * N + n] = v + bias[n] + add0[(size_t)m * N + n] + add1[(size_t)m * N + n];
    }
}

// ---------------- RoPE in place on q and k (row-major [B][NE]) ----------------
__global__ void rope_kernel(float* __restrict__ q, float* __restrict__ k,
    const int* __restrict__ pos_ids)
{
    int b = blockIdx.x;
    int t = threadIdx.x;          // 0..511
    int h = t >> 5, i = t & 31;
    float pos = (float)pos_ids[b];
    float freq = powf(10000.f, -(float)(2 * i) / (float)RDIM);
    float ang = pos * freq;
    float sn, cs;
    sincosf(ang, &sn, &cs);
    size_t base = (size_t)b * NEMB + (size_t)h * DD + 2 * i;
    float q1 = q[base], q2 = q[base + 1];
    q[base] = q1 * cs - q2 * sn;
    q[base + 1] = q2 * cs + q1 * sn;
    float k1 = k[base], k2 = k[base + 1];
    k[base] = k1 * cs - k2 * sn;
    k[base + 1] = k2 * cs + k1 * sn;
}

// ---------------- cache-override maps ----------------
__global__ void ov_init_kernel(int* __restrict__ ovk, int* __restrict__ ovv)
{
    int i = blockIdx.x * 256 + threadIdx.x;
    if (i < NSLOTS) { ovk[i] = -1; ovv[i] = -1; }
}
__global__ void ov_scatter_kernel(int* __restrict__ ovk, int* __restrict__ ovv,
    const int* __restrict__ nkl, const int* __restrict__ nvl)
{
    int j = threadIdx.x;
    if (j < BB) {
        atomicMax(&ovk[nkl[j]], j);
        atomicMax(&ovv[nvl[j]], j);
    }
}

// ---------------- attention partials: block = (b,h,chunk of 128 kv rows) ----------------
__global__ __launch_bounds__(256) void attn_part_kernel(const float* __restrict__ q,
    const float* __restrict__ knew, const float* __restrict__ vnew,
    const float* __restrict__ kcache, const float* __restrict__ vcache,
    const int* __restrict__ kidx, const int* __restrict__ vidx,
    const int* __restrict__ ovk, const int* __restrict__ ovv,
    const float* __restrict__ mask,
    float* __restrict__ pm, float* __restrict__ pl, float* __restrict__ pctx)
{
    int b = blockIdx.x >> 4, h = blockIdx.x & 15, c = blockIdx.y;
    int t = threadIdx.x;
    __shared__ float qs[DD];
    __shared__ float sc[CH];
    __shared__ const float* kp[CH];
    __shared__ const float* vp[CH];
    __shared__ float red[4];

    qs[t] = q[(size_t)b * NEMB + (size_t)h * DD + t];
    if (t < CH) {
        int l = c * CH + t;
        int ks = kidx[b * KVLEN + l];
        int vs = vidx[b * KVLEN + l];
        int ok = ovk[ks], ov = ovv[vs];
        kp[t] = (ok >= 0) ? (knew + (size_t)ok * NEMB + (size_t)h * DD)
                          : (kcache + (size_t)ks * NEMB + (size_t)h * DD);
        vp[t] = (ov >= 0) ? (vnew + (size_t)ov * NEMB + (size_t)h * DD)
                          : (vcache + (size_t)vs * NEMB + (size_t)h * DD);
    }
    __syncthreads();

    int wave = t >> 6, lane = t & 63;
    float4 qf = *(const float4*)(qs + lane * 4);
#pragma unroll 4
    for (int l = wave; l < CH; l += 4) {
        const float4 kf = *(const float4*)(kp[l] + lane * 4);
        float d = fmaf(kf.x, qf.x, fmaf(kf.y, qf.y, fmaf(kf.z, qf.z, kf.w * qf.w)));
#pragma unroll
        for (int o = 32; o > 0; o >>= 1) d += __shfl_xor(d, o, 64);
        if (lane == 0) sc[l] = d * 0.0625f + mask[b * KVLEN + c * CH + l];
    }
    __syncthreads();

    float sv = sc[t & (CH - 1)];
    float mx = sv;
#pragma unroll
    for (int o = 32; o > 0; o >>= 1) mx = fmaxf(mx, __shfl_xor(mx, o, 64));
    if (lane == 0) red[wave] = mx;
    __syncthreads();
    float bmax = fmaxf(fmaxf(red[0], red[1]), fmaxf(red[2], red[3]));
    float e = (t < CH) ? expf(sv - bmax) : 0.f;
    float sm = e;
#pragma unroll
    for (int o = 32; o > 0; o >>= 1) sm += __shfl_xor(sm, o, 64);
    __syncthreads();
    if (lane == 0) red[wave] = sm;
    __syncthreads();
    float lsum = red[0] + red[1] + red[2] + red[3];
    if (t < CH) sc[t] = e;
    __syncthreads();

    float acc = 0.f;
#pragma unroll 8
    for (int l = 0; l < CH; ++l)
        acc = fmaf(sc[l], vp[l][t], acc);

    int pi = blockIdx.x * NCH + c;
    pctx[(size_t)pi * DD + t] = acc;
    if (t == 0) { pm[pi] = bmax; pl[pi] = lsum; }
}

// ---------------- attention combine: block = (b,h) ----------------
__global__ __launch_bounds__(256) void attn_comb_kernel(const float* __restrict__ pm,
    const float* __restrict__ pl, const float* __restrict__ pctx,
    float* __restrict__ ctxT)
{
    int bh = blockIdx.x;
    int b = bh >> 4, h = bh & 15;
    int t = threadIdx.x;
    float M = -INFINITY;
#pragma unroll
    for (int c = 0; c < NCH; ++c) M = fmaxf(M, pm[bh * NCH + c]);
    float L = 0.f, acc = 0.f;
#pragma unroll
    for (int c = 0; c < NCH; ++c) {
        float wv = expf(pm[bh * NCH + c] - M);
        L += pl[bh * NCH + c] * wv;
        acc += pctx[((size_t)bh * NCH + c) * DD + t] * wv;
    }
    ctxT[((size_t)h * DD + t) * BB + b] = acc / L;
}

extern "C" void kernel_launch(void* const* d_in, const int* in_sizes, int n_in,
                              void* d_out, int out_size, void* d_ws, size_t ws_size,
                              hipStream_t stream)
{
    (void)in_sizes; (void)n_in; (void)out_size; (void)ws_size;
    const float* hs      = (const float*)d_in[0];
    const float* kcache  = (const float*)d_in[1];
    const float* vcache  = (const float*)d_in[2];
    const float* ln_w    = (const float*)d_in[3];
    const float* ln_b    = (const float*)d_in[4];
    const float* wq      = (const float*)d_in[5];
    const float* wk      = (const float*)d_in[6];
    const float* wv      = (const float*)d_in[7];
    const float* wo      = (const float*)d_in[8];
    const float* fc_in_w = (const float*)d_in[9];
    const float* fc_in_b = (const float*)d_in[10];
    const float* fc_out_w= (const float*)d_in[11];
    const float* fc_out_b= (const float*)d_in[12];
    const float* mask    = (const float*)d_in[13];
    const int* nkl       = (const int*)d_in[14];
    const int* nvl       = (const int*)d_in[15];
    const int* kidx      = (const int*)d_in[16];
    const int* vidx      = (const int*)d_in[17];
    const int* pos       = (const int*)d_in[18];
    float* out = (float*)d_out;

    char* ws = (char*)d_ws;
    float* hT      = (float*)ws; ws += (size_t)NEMB * BB * 4;
    float* qb      = (float*)ws; ws += (size_t)BB * NEMB * 4;
    float* kb      = (float*)ws; ws += (size_t)BB * NEMB * 4;
    float* vb      = (float*)ws; ws += (size_t)BB * NEMB * 4;
    float* ctxT    = (float*)ws; ws += (size_t)NEMB * BB * 4;
    float* attn_o  = (float*)ws; ws += (size_t)BB * NEMB * 4;
    float* mT      = (float*)ws; ws += (size_t)NINT * BB * 4;
    int*   ovk     = (int*)ws;   ws += (size_t)NSLOTS * 4;
    int*   ovv     = (int*)ws;   ws += (size_t)NSLOTS * 4;
    float* pm      = (float*)ws; ws += (size_t)BB * HH * NCH * 4;
    float* pl      = (float*)ws; ws += (size_t)BB * HH * NCH * 4;
    float* pctx    = (float*)ws; ws += (size_t)BB * HH * NCH * DD * 4;
    float* P       = (float*)ws;

    ln_kernel<<<BB, 256, 0, stream>>>(hs, ln_w, ln_b, hT);
    ov_init_kernel<<<NSLOTS / 256, 256, 0, stream>>>(ovk, ovv);
    ov_scatter_kernel<<<1, 64, 0, stream>>>(ovk, ovv, nkl, nvl);

    // QKV: N=4096, K=4096, S=16 chunk 256; z = widx*2+mhalf
    gemm16_kernel<<<dim3(4, 16, 6), 256, 0, stream>>>(hT, wq, wk, wv, P, NEMB, 256);
    size_t psl = (size_t)16 * 32 * NEMB;
    reduce2_kernel<0><<<dim3(16, 32), 256, 0, stream>>>(P,           16, NEMB, nullptr, nullptr, nullptr, qb);
    reduce2_kernel<0><<<dim3(16, 32), 256, 0, stream>>>(P + psl,     16, NEMB, nullptr, nullptr, nullptr, kb);
    reduce2_kernel<0><<<dim3(16, 32), 256, 0, stream>>>(P + 2 * psl, 16, NEMB, nullptr, nullptr, nullptr, vb);

    rope_kernel<<<BB, 512, 0, stream>>>(qb, kb, pos);

    attn_part_kernel<<<dim3(BB * HH, NCH), 256, 0, stream>>>(qb, kb, vb, kcache, vcache,
                                                             kidx, vidx, ovk, ovv, mask,
                                                             pm, pl, pctx);
    attn_comb_kernel<<<BB * HH, 256, 0, stream>>>(pm, pl, pctx, ctxT);

    // Wo: N=4096, K=4096, S=32 chunk 128
    gemm16_kernel<<<dim3(4, 32, 2), 256, 0, stream>>>(ctxT, wo, wo, wo, P, NEMB, 128);
    reduce2_kernel<0><<<dim3(16, 32), 256, 0, stream>>>(P, 32, NEMB, nullptr, nullptr, nullptr, attn_o);

    // fc_in: N=16384, K=4096, S=8 chunk 512 -> gelu -> mT [NI][32]
    gemm16_kernel<<<dim3(16, 8, 2), 256, 0, stream>>>(hT, fc_in_w, fc_in_w, fc_in_w, P, NINT, 512);
    reduce2_kernel<1><<<dim3(64, 32), 256, 0, stream>>>(P, 8, NINT, fc_in_b, nullptr, nullptr, mT);

    // fc_out: N=4096, K=16384, S=32 chunk 512; fused bias + attn_out + residual
    gemm16_kernel<<<dim3(4, 32, 2), 256, 0, stream>>>(mT, fc_out_w, fc_out_w, fc_out_w, P, NEMB, 512);
    reduce2_kernel<2><<<dim3(16, 32), 256, 0, stream>>>(P, 32, NEMB, fc_out_b, attn_o, hs, out);
}

// Round 3
// 568.687 us; speedup vs baseline: 2.0251x; 1.1979x over previous
//
#include <hip/hip_runtime.h>
#include <math.h>

#define BB 32
#define HH 16
#define DD 256
#define RDIM 64
#define NEMB 4096
#define NINT 16384
#define NSLOTS 32768
#define KVLEN 1024
#define LNEPS 1e-5f
#define NCH 8
#define CH 128

// ---------------- LayerNorm -> hT [NE][32] (A-transposed for GEMM) ----------------
__global__ __launch_bounds__(256) void ln_kernel(const float* __restrict__ x,
    const float* __restrict__ lw, const float* __restrict__ lb,
    float* __restrict__ hT)
{
    int b = blockIdx.x;
    int t = threadIdx.x;
    const float* row = x + (size_t)b * NEMB;
    float4 v[4];
    float sum = 0.f, sq = 0.f;
#pragma unroll
    for (int j = 0; j < 4; ++j) {
        v[j] = *(const float4*)(row + t * 4 + j * 1024);
        sum += v[j].x + v[j].y + v[j].z + v[j].w;
        sq += v[j].x * v[j].x + v[j].y * v[j].y + v[j].z * v[j].z + v[j].w * v[j].w;
    }
    __shared__ float s1[4], s2[4];
#pragma unroll
    for (int o = 32; o > 0; o >>= 1) {
        sum += __shfl_xor(sum, o, 64);
        sq += __shfl_xor(sq, o, 64);
    }
    int wave = t >> 6, lane = t & 63;
    if (lane == 0) { s1[wave] = sum; s2[wave] = sq; }
    __syncthreads();
    sum = s1[0] + s1[1] + s1[2] + s1[3];
    sq = s2[0] + s2[1] + s2[2] + s2[3];
    float mu = sum / NEMB;
    float var = sq / NEMB - mu * mu;
    float rstd = rsqrtf(var + LNEPS);
#pragma unroll
    for (int j = 0; j < 4; ++j) {
        int n = t * 4 + j * 1024;
        float4 wv = *(const float4*)(lw + n);
        float4 bv = *(const float4*)(lb + n);
        hT[(size_t)(n + 0) * BB + b] = (v[j].x - mu) * rstd * wv.x + bv.x;
        hT[(size_t)(n + 1) * BB + b] = (v[j].y - mu) * rstd * wv.y + bv.y;
        hT[(size_t)(n + 2) * BB + b] = (v[j].z - mu) * rstd * wv.z + bv.z;
        hT[(size_t)(n + 3) * BB + b] = (v[j].w - mu) * rstd * wv.w + bv.w;
    }
}

// ---------------- Skinny GEMM: thread = 2n x 32m; single pass over W ----------------
// grid: x = N/512, y = S (k-chunks), z = widx. P[z][(s*32+m)*N + n]
__global__ __launch_bounds__(256) void gemm32_kernel(const float* __restrict__ AT,
    const float* __restrict__ W0, const float* __restrict__ W1, const float* __restrict__ W2,
    float* __restrict__ P, int N, int kChunk)
{
    const float* W = W0;
    if (blockIdx.z == 1) W = W1;
    else if (blockIdx.z == 2) W = W2;
    int n = (blockIdx.x * 256 + threadIdx.x) * 2;
    int s = blockIdx.y, S = gridDim.y;
    size_t k0 = (size_t)s * kChunk;
    float2 acc[32];
#pragma unroll
    for (int mi = 0; mi < 32; ++mi) acc[mi] = make_float2(0.f, 0.f);
    const float* w = W + k0 * N + n;
    const float* a = AT + k0 * 32;   // wave-uniform, contiguous 128B per k
#pragma unroll 4
    for (int kk = 0; kk < kChunk; ++kk) {
        float2 wv = *(const float2*)w;
#pragma unroll
        for (int mi = 0; mi < 32; ++mi) {
            float am = a[mi];
            acc[mi].x = fmaf(am, wv.x, acc[mi].x);
            acc[mi].y = fmaf(am, wv.y, acc[mi].y);
        }
        w += N;
        a += 32;
    }
    float* p = P + (size_t)blockIdx.z * ((size_t)S * 32 * N) + ((size_t)s * 32) * N + n;
#pragma unroll
    for (int mi = 0; mi < 32; ++mi)
        *(float2*)(p + (size_t)mi * N) = acc[mi];
}

__device__ inline float gelu_tanh(float x)
{
    float x3 = x * x * x;
    return 0.5f * x * (1.f + tanhf(0.7978845608028654f * (x + 0.044715f * x3)));
}

// ---------------- merged QKV reduce: grid (N/256, 32, 3) ----------------
__global__ __launch_bounds__(256) void qkv_reduce_kernel(const float* __restrict__ P,
    int S, float* __restrict__ q, float* __restrict__ k, float* __restrict__ v)
{
    int n = blockIdx.x * 256 + threadIdx.x;
    int m = blockIdx.y;
    int w = blockIdx.z;
    const float* p = P + (size_t)w * ((size_t)S * 32 * NEMB) + (size_t)m * NEMB + n;
    float s = 0.f;
#pragma unroll 4
    for (int i = 0; i < S; ++i) { s += *p; p += (size_t)32 * NEMB; }
    float* o = (w == 0) ? q : (w == 1) ? k : v;
    o[(size_t)m * NEMB + n] = s;
}

// MODE 0: out[m][N]   MODE 1: gelu(v+bias) -> out[n][32]   MODE 2: v+bias+add0+add1 -> out[m][N]
template<int MODE>
__global__ __launch_bounds__(256) void reduce2_kernel(
    const float* __restrict__ P, int S, int N,
    const float* __restrict__ bias, const float* __restrict__ add0,
    const float* __restrict__ add1, float* __restrict__ out)
{
    int n = blockIdx.x * 256 + threadIdx.x;
    int m = blockIdx.y;
    float v = 0.f;
    const float* p = P + (size_t)m * N + n;
#pragma unroll 4
    for (int s = 0; s < S; ++s) {
        v += *p;
        p += (size_t)32 * N;
    }
    if (MODE == 0) {
        out[(size_t)m * N + n] = v;
    } else if (MODE == 1) {
        out[(size_t)n * 32 + m] = gelu_tanh(v + bias[n]);
    } else {
        out[(size_t)m * N + n] = v + bias[n] + add0[(size_t)m * N + n] + add1[(size_t)m * N + n];
    }
}

// ---------------- RoPE in place on q and k (row-major [B][NE]) ----------------
__global__ void rope_kernel(float* __restrict__ q, float* __restrict__ k,
    const int* __restrict__ pos_ids)
{
    int b = blockIdx.x;
    int t = threadIdx.x;          // 0..511
    int h = t >> 5, i = t & 31;
    float pos = (float)pos_ids[b];
    float freq = powf(10000.f, -(float)(2 * i) / (float)RDIM);
    float ang = pos * freq;
    float sn, cs;
    sincosf(ang, &sn, &cs);
    size_t base = (size_t)b * NEMB + (size_t)h * DD + 2 * i;
    float q1 = q[base], q2 = q[base + 1];
    q[base] = q1 * cs - q2 * sn;
    q[base + 1] = q2 * cs + q1 * sn;
    float k1 = k[base], k2 = k[base + 1];
    k[base] = k1 * cs - k2 * sn;
    k[base + 1] = k2 * cs + k1 * sn;
}

// ---------------- cache-override maps ----------------
__global__ void ov_init_kernel(int* __restrict__ ovk, int* __restrict__ ovv)
{
    int i = blockIdx.x * 256 + threadIdx.x;
    if (i < NSLOTS) { ovk[i] = -1; ovv[i] = -1; }
}
__global__ void ov_scatter_kernel(int* __restrict__ ovk, int* __restrict__ ovv,
    const int* __restrict__ nkl, const int* __restrict__ nvl)
{
    int j = threadIdx.x;
    if (j < BB) {
        atomicMax(&ovk[nkl[j]], j);
        atomicMax(&ovv[nvl[j]], j);
    }
}

// ---------------- attention partials: block = (b,h,chunk of 128 kv rows) ----------------
__global__ __launch_bounds__(256) void attn_part_kernel(const float* __restrict__ q,
    const float* __restrict__ knew, const float* __restrict__ vnew,
    const float* __restrict__ kcache, const float* __restrict__ vcache,
    const int* __restrict__ kidx, const int* __restrict__ vidx,
    const int* __restrict__ ovk, const int* __restrict__ ovv,
    const float* __restrict__ mask,
    float* __restrict__ pm, float* __restrict__ pl, float* __restrict__ pctx)
{
    int b = blockIdx.x >> 4, h = blockIdx.x & 15, c = blockIdx.y;
    int t = threadIdx.x;
    __shared__ float qs[DD];
    __shared__ float sc[CH];
    __shared__ const float* kp[CH];
    __shared__ const float* vp[CH];
    __shared__ float red[4];
    __shared__ float cx[4][DD];

    qs[t] = q[(size_t)b * NEMB + (size_t)h * DD + t];
    if (t < CH) {
        int l = c * CH + t;
        int ks = kidx[b * KVLEN + l];
        int vs = vidx[b * KVLEN + l];
        int ok = ovk[ks], ov = ovv[vs];
        kp[t] = (ok >= 0) ? (knew + (size_t)ok * NEMB + (size_t)h * DD)
                          : (kcache + (size_t)ks * NEMB + (size_t)h * DD);
        vp[t] = (ov >= 0) ? (vnew + (size_t)ov * NEMB + (size_t)h * DD)
                          : (vcache + (size_t)vs * NEMB + (size_t)h * DD);
    }
    __syncthreads();

    int wave = t >> 6, lane = t & 63;
    float4 qf = *(const float4*)(qs + lane * 4);
#pragma unroll 4
    for (int l = wave; l < CH; l += 4) {
        const float4 kf = *(const float4*)(kp[l] + lane * 4);
        float d = fmaf(kf.x, qf.x, fmaf(kf.y, qf.y, fmaf(kf.z, qf.z, kf.w * qf.w)));
#pragma unroll
        for (int o = 32; o > 0; o >>= 1) d += __shfl_xor(d, o, 64);
        if (lane == 0) sc[l] = d * 0.0625f + mask[b * KVLEN + c * CH + l];
    }
    __syncthreads();

    float sv = sc[t & (CH - 1)];
    float mx = sv;
#pragma unroll
    for (int o = 32; o > 0; o >>= 1) mx = fmaxf(mx, __shfl_xor(mx, o, 64));
    if (lane == 0) red[wave] = mx;
    __syncthreads();
    float bmax = fmaxf(fmaxf(red[0], red[1]), fmaxf(red[2], red[3]));
    float e = (t < CH) ? expf(sv - bmax) : 0.f;
    float sm = e;
#pragma unroll
    for (int o = 32; o > 0; o >>= 1) sm += __shfl_xor(sm, o, 64);
    __syncthreads();
    if (lane == 0) red[wave] = sm;
    __syncthreads();
    float lsum = red[0] + red[1] + red[2] + red[3];
    if (t < CH) sc[t] = e;
    __syncthreads();

    // PV: wave-per-row, float4 per lane (1KB row per load instruction set)
    float4 a4 = make_float4(0.f, 0.f, 0.f, 0.f);
#pragma unroll 4
    for (int l = wave; l < CH; l += 4) {
        float4 vf = *(const float4*)(vp[l] + lane * 4);
        float pw = sc[l];
        a4.x = fmaf(pw, vf.x, a4.x);
        a4.y = fmaf(pw, vf.y, a4.y);
        a4.z = fmaf(pw, vf.z, a4.z);
        a4.w = fmaf(pw, vf.w, a4.w);
    }
    *(float4*)(&cx[wave][lane * 4]) = a4;
    __syncthreads();

    int pi = blockIdx.x * NCH + c;
    pctx[(size_t)pi * DD + t] = cx[0][t] + cx[1][t] + cx[2][t] + cx[3][t];
    if (t == 0) { pm[pi] = bmax; pl[pi] = lsum; }
}

// ---------------- attention combine: block = (b,h) ----------------
__global__ __launch_bounds__(256) void attn_comb_kernel(const float* __restrict__ pm,
    const float* __restrict__ pl, const float* __restrict__ pctx,
    float* __restrict__ ctxT)
{
    int bh = blockIdx.x;
    int b = bh >> 4, h = bh & 15;
    int t = threadIdx.x;
    float M = -INFINITY;
#pragma unroll
    for (int c = 0; c < NCH; ++c) M = fmaxf(M, pm[bh * NCH + c]);
    float L = 0.f, acc = 0.f;
#pragma unroll
    for (int c = 0; c < NCH; ++c) {
        float wv = expf(pm[bh * NCH + c] - M);
        L += pl[bh * NCH + c] * wv;
        acc += pctx[((size_t)bh * NCH + c) * DD + t] * wv;
    }
    ctxT[((size_t)h * DD + t) * BB + b] = acc / L;
}

extern "C" void kernel_launch(void* const* d_in, const int* in_sizes, int n_in,
                              void* d_out, int out_size, void* d_ws, size_t ws_size,
                              hipStream_t stream)
{
    (void)in_sizes; (void)n_in; (void)out_size; (void)ws_size;
    const float* hs      = (const float*)d_in[0];
    const float* kcache  = (const float*)d_in[1];
    const float* vcache  = (const float*)d_in[2];
    const float* ln_w    = (const float*)d_in[3];
    const float* ln_b    = (const float*)d_in[4];
    const float* wq      = (const float*)d_in[5];
    const float* wk      = (const float*)d_in[6];
    const float* wv      = (const float*)d_in[7];
    const float* wo      = (const float*)d_in[8];
    const float* fc_in_w = (const float*)d_in[9];
    const float* fc_in_b = (const float*)d_in[10];
    const float* fc_out_w= (const float*)d_in[11];
    const float* fc_out_b= (const float*)d_in[12];
    const float* mask    = (const float*)d_in[13];
    const int* nkl       = (const int*)d_in[14];
    const int* nvl       = (const int*)d_in[15];
    const int* kidx      = (const int*)d_in[16];
    const int* vidx      = (const int*)d_in[17];
    const int* pos       = (const int*)d_in[18];
    float* out = (float*)d_out;

    char* ws = (char*)d_ws;
    float* hT      = (float*)ws; ws += (size_t)NEMB * BB * 4;
    float* qb      = (float*)ws; ws += (size_t)BB * NEMB * 4;
    float* kb      = (float*)ws; ws += (size_t)BB * NEMB * 4;
    float* vb      = (float*)ws; ws += (size_t)BB * NEMB * 4;
    float* ctxT    = (float*)ws; ws += (size_t)NEMB * BB * 4;
    float* attn_o  = (float*)ws; ws += (size_t)BB * NEMB * 4;
    float* mT      = (float*)ws; ws += (size_t)NINT * BB * 4;
    int*   ovk     = (int*)ws;   ws += (size_t)NSLOTS * 4;
    int*   ovv     = (int*)ws;   ws += (size_t)NSLOTS * 4;
    float* pm      = (float*)ws; ws += (size_t)BB * HH * NCH * 4;
    float* pl      = (float*)ws; ws += (size_t)BB * HH * NCH * 4;
    float* pctx    = (float*)ws; ws += (size_t)BB * HH * NCH * DD * 4;
    float* P       = (float*)ws;

    ln_kernel<<<BB, 256, 0, stream>>>(hs, ln_w, ln_b, hT);
    ov_init_kernel<<<NSLOTS / 256, 256, 0, stream>>>(ovk, ovv);
    ov_scatter_kernel<<<1, 64, 0, stream>>>(ovk, ovv, nkl, nvl);

    // QKV: N=4096, S=16 chunk 256, z = widx -> 384 blocks
    gemm32_kernel<<<dim3(8, 16, 3), 256, 0, stream>>>(hT, wq, wk, wv, P, NEMB, 256);
    qkv_reduce_kernel<<<dim3(16, 32, 3), 256, 0, stream>>>(P, 16, qb, kb, vb);

    rope_kernel<<<BB, 512, 0, stream>>>(qb, kb, pos);

    attn_part_kernel<<<dim3(BB * HH, NCH), 256, 0, stream>>>(qb, kb, vb, kcache, vcache,
                                                             kidx, vidx, ovk, ovv, mask,
                                                             pm, pl, pctx);
    attn_comb_kernel<<<BB * HH, 256, 0, stream>>>(pm, pl, pctx, ctxT);

    // Wo: N=4096, S=64 chunk 64 -> 512 blocks
    gemm32_kernel<<<dim3(8, 64, 1), 256, 0, stream>>>(ctxT, wo, wo, wo, P, NEMB, 64);
    reduce2_kernel<0><<<dim3(16, 32), 256, 0, stream>>>(P, 64, NEMB, nullptr, nullptr, nullptr, attn_o);

    // fc_in: N=16384, S=16 chunk 256 -> 512 blocks; gelu -> mT [NI][32]
    gemm32_kernel<<<dim3(32, 16, 1), 256, 0, stream>>>(hT, fc_in_w, fc_in_w, fc_in_w, P, NINT, 256);
    reduce2_kernel<1><<<dim3(64, 32), 256, 0, stream>>>(P, 16, NINT, fc_in_b, nullptr, nullptr, mT);

    // fc_out: N=4096, K=16384, S=64 chunk 256 -> 512 blocks; fused bias + attn_out + residual
    gemm32_kernel<<<dim3(8, 64, 1), 256, 0, stream>>>(mT, fc_out_w, fc_out_w, fc_out_w, P, NEMB, 256);
    reduce2_kernel<2><<<dim3(16, 32), 256, 0, stream>>>(P, 64, NEMB, fc_out_b, attn_o, hs, out);
}

// Round 4
// 541.867 us; speedup vs baseline: 2.1253x; 1.0495x over previous
//
#include <hip/hip_runtime.h>
#include <math.h>

#define BB 32
#define HH 16
#define DD 256
#define RDIM 64
#define NEMB 4096
#define NINT 16384
#define NSLOTS 32768
#define KVLEN 1024
#define LNEPS 1e-5f
#define NCH 16
#define CH 64

// ---------------- LayerNorm -> hT [NE][32] (A-transposed for GEMM) ----------------
__global__ __launch_bounds__(256) void ln_kernel(const float* __restrict__ x,
    const float* __restrict__ lw, const float* __restrict__ lb,
    float* __restrict__ hT)
{
    int b = blockIdx.x;
    int t = threadIdx.x;
    const float* row = x + (size_t)b * NEMB;
    float4 v[4];
    float sum = 0.f, sq = 0.f;
#pragma unroll
    for (int j = 0; j < 4; ++j) {
        v[j] = *(const float4*)(row + t * 4 + j * 1024);
        sum += v[j].x + v[j].y + v[j].z + v[j].w;
        sq += v[j].x * v[j].x + v[j].y * v[j].y + v[j].z * v[j].z + v[j].w * v[j].w;
    }
    __shared__ float s1[4], s2[4];
#pragma unroll
    for (int o = 32; o > 0; o >>= 1) {
        sum += __shfl_xor(sum, o, 64);
        sq += __shfl_xor(sq, o, 64);
    }
    int wave = t >> 6, lane = t & 63;
    if (lane == 0) { s1[wave] = sum; s2[wave] = sq; }
    __syncthreads();
    sum = s1[0] + s1[1] + s1[2] + s1[3];
    sq = s2[0] + s2[1] + s2[2] + s2[3];
    float mu = sum / NEMB;
    float var = sq / NEMB - mu * mu;
    float rstd = rsqrtf(var + LNEPS);
#pragma unroll
    for (int j = 0; j < 4; ++j) {
        int n = t * 4 + j * 1024;
        float4 wv = *(const float4*)(lw + n);
        float4 bv = *(const float4*)(lb + n);
        hT[(size_t)(n + 0) * BB + b] = (v[j].x - mu) * rstd * wv.x + bv.x;
        hT[(size_t)(n + 1) * BB + b] = (v[j].y - mu) * rstd * wv.y + bv.y;
        hT[(size_t)(n + 2) * BB + b] = (v[j].z - mu) * rstd * wv.z + bv.z;
        hT[(size_t)(n + 3) * BB + b] = (v[j].w - mu) * rstd * wv.w + bv.w;
    }
}

// ---------------- shared GEMM body: thread = 2n x 32m ----------------
__device__ __forceinline__ void gemm_body(const float* __restrict__ AT,
    const float* __restrict__ W, float* __restrict__ P,
    int N, int kChunk, int x, int s)
{
    int n = (x * 256 + threadIdx.x) * 2;
    size_t k0 = (size_t)s * kChunk;
    float2 acc[32];
#pragma unroll
    for (int mi = 0; mi < 32; ++mi) acc[mi] = make_float2(0.f, 0.f);
    const float* w = W + k0 * N + n;
    const float* a = AT + k0 * 32;   // wave-uniform, contiguous 128B per k
#pragma unroll 4
    for (int kk = 0; kk < kChunk; ++kk) {
        float2 wv = *(const float2*)w;
#pragma unroll
        for (int mi = 0; mi < 32; ++mi) {
            float am = a[mi];
            acc[mi].x = fmaf(am, wv.x, acc[mi].x);
            acc[mi].y = fmaf(am, wv.y, acc[mi].y);
        }
        w += N;
        a += 32;
    }
    float* p = P + ((size_t)s * 32) * N + n;
#pragma unroll
    for (int mi = 0; mi < 32; ++mi)
        *(float2*)(p + (size_t)mi * N) = acc[mi];
}

// QKV: grid (8, 32, 3): x, s, widx
__global__ __launch_bounds__(256) void gemm_qkv_kernel(const float* __restrict__ AT,
    const float* __restrict__ W0, const float* __restrict__ W1, const float* __restrict__ W2,
    float* __restrict__ P)
{
    const float* W = (blockIdx.z == 0) ? W0 : (blockIdx.z == 1) ? W1 : W2;
    float* Pz = P + (size_t)blockIdx.z * ((size_t)32 * 32 * NEMB);
    gemm_body(AT, W, Pz, NEMB, 128, blockIdx.x, blockIdx.y);
}

// Wo (id<512: x=8, s=64, chunk 64) + fc_in (x=32, s=16, chunk 256)
__global__ __launch_bounds__(256) void gemm_dual_kernel(
    const float* __restrict__ ctxT, const float* __restrict__ wo, float* __restrict__ P0,
    const float* __restrict__ hT, const float* __restrict__ fciw, float* __restrict__ P1)
{
    int id = blockIdx.x;
    if (id < 512) gemm_body(ctxT, wo, P0, NEMB, 64, id & 7, id >> 3);
    else { id -= 512; gemm_body(hT, fciw, P1, NINT, 256, id & 31, id >> 5); }
}

// fc_out: grid (8, 64)
__global__ __launch_bounds__(256) void gemm_fcout_kernel(const float* __restrict__ AT,
    const float* __restrict__ W, float* __restrict__ P)
{
    gemm_body(AT, W, P, NEMB, 256, blockIdx.x, blockIdx.y);
}

__device__ inline float gelu_tanh(float x)
{
    float x3 = x * x * x;
    return 0.5f * x * (1.f + tanhf(0.7978845608028654f * (x + 0.044715f * x3)));
}

// ---------------- QKV reduce + RoPE fused; float2/thread; grid (8, 32, 3) ----------------
__global__ __launch_bounds__(256) void qkv_rr_kernel(const float* __restrict__ P,
    float* __restrict__ q, float* __restrict__ k, float* __restrict__ v,
    const int* __restrict__ pos)
{
    int w = blockIdx.z;
    int m = blockIdx.y;
    int n0 = (blockIdx.x * 256 + threadIdx.x) * 2;
    const float* p = P + (size_t)w * ((size_t)32 * 32 * NEMB) + (size_t)m * NEMB + n0;
    float sx = 0.f, sy = 0.f;
#pragma unroll 4
    for (int i = 0; i < 32; ++i) {
        float2 u = *(const float2*)p;
        sx += u.x; sy += u.y;
        p += (size_t)32 * NEMB;
    }
    int d = n0 & (DD - 1);
    if (w < 2 && d < RDIM) {
        int i = d >> 1;
        float fr = exp2f((float)i * (-13.287712379549449f / 32.f)); // 10000^(-i/32)
        float ang = (float)pos[m] * fr;
        float sn, cs;
        sincosf(ang, &sn, &cs);
        float x1 = sx, x2 = sy;
        sx = x1 * cs - x2 * sn;
        sy = x2 * cs + x1 * sn;
    }
    float* o = (w == 0) ? q : (w == 1) ? k : v;
    *(float2*)(o + (size_t)m * NEMB + n0) = make_float2(sx, sy);
}

// Wo reduce (bx<16) + fc_in reduce w/ gelu (bx>=16); grid (80, 32)
__global__ __launch_bounds__(256) void reduce_dual_kernel(
    const float* __restrict__ P0, const float* __restrict__ P1,
    const float* __restrict__ fcib, float* __restrict__ attn_o, float* __restrict__ mT)
{
    int bx = blockIdx.x, m = blockIdx.y, t = threadIdx.x;
    if (bx < 16) {
        int n = bx * 256 + t;
        const float* p = P0 + (size_t)m * NEMB + n;
        float s = 0.f;
#pragma unroll 4
        for (int i = 0; i < 64; ++i) { s += *p; p += (size_t)32 * NEMB; }
        attn_o[(size_t)m * NEMB + n] = s;
    } else {
        int n = (bx - 16) * 256 + t;
        const float* p = P1 + (size_t)m * NINT + n;
        float s = 0.f;
#pragma unroll 4
        for (int i = 0; i < 16; ++i) { s += *p; p += (size_t)32 * NINT; }
        mT[(size_t)n * 32 + m] = gelu_tanh(s + fcib[n]);
    }
}

// fc_out reduce: v + bias + attn_o + residual; grid (16, 32)
__global__ __launch_bounds__(256) void reduce_final_kernel(const float* __restrict__ P,
    const float* __restrict__ bias, const float* __restrict__ attn_o,
    const float* __restrict__ resid, float* __restrict__ out)
{
    int n = blockIdx.x * 256 + threadIdx.x;
    int m = blockIdx.y;
    const float* p = P + (size_t)m * NEMB + n;
    float s = 0.f;
#pragma unroll 4
    for (int i = 0; i < 64; ++i) { s += *p; p += (size_t)32 * NEMB; }
    out[(size_t)m * NEMB + n] = s + bias[n] + attn_o[(size_t)m * NEMB + n]
                              + resid[(size_t)m * NEMB + n];
}

// ---------------- attention partials: block = (b,h,chunk of 64 kv rows) ----------------
__global__ __launch_bounds__(256) void attn_part_kernel(const float* __restrict__ q,
    const float* __restrict__ knew, const float* __restrict__ vnew,
    const float* __restrict__ kcache, const float* __restrict__ vcache,
    const int* __restrict__ kidx, const int* __restrict__ vidx,
    const int* __restrict__ nkl, const int* __restrict__ nvl,
    const float* __restrict__ mask,
    float* __restrict__ pm, float* __restrict__ pl, float* __restrict__ pctx)
{
    int b = blockIdx.x >> 4, h = blockIdx.x & 15, c = blockIdx.y;
    int t = threadIdx.x;
    __shared__ float qs[DD];
    __shared__ float sc[CH];
    __shared__ const float* kp[CH];
    __shared__ const float* vp[CH];
    __shared__ float cx[4][DD];

    qs[t] = q[(size_t)b * NEMB + (size_t)h * DD + t];
    if (t < CH) {
        int l = c * CH + t;
        int ks = kidx[b * KVLEN + l];
        int vs = vidx[b * KVLEN + l];
        const float* kbase = kcache + (size_t)ks * NEMB;
        const float* vbase = vcache + (size_t)vs * NEMB;
#pragma unroll
        for (int j = 0; j < BB; ++j) {
            if (nkl[j] == ks) kbase = knew + (size_t)j * NEMB;
            if (nvl[j] == vs) vbase = vnew + (size_t)j * NEMB;
        }
        kp[t] = kbase + (size_t)h * DD;
        vp[t] = vbase + (size_t)h * DD;
    }
    __syncthreads();

    int wave = t >> 6, lane = t & 63;
    float4 qf = *(const float4*)(qs + lane * 4);
#pragma unroll 4
    for (int l = wave; l < CH; l += 4) {
        const float4 kf = *(const float4*)(kp[l] + lane * 4);
        float d = fmaf(kf.x, qf.x, fmaf(kf.y, qf.y, fmaf(kf.z, qf.z, kf.w * qf.w)));
#pragma unroll
        for (int o = 32; o > 0; o >>= 1) d += __shfl_xor(d, o, 64);
        if (lane == 0) sc[l] = d * 0.0625f + mask[b * KVLEN + c * CH + l];
    }
    __syncthreads();

    // each wave's 64 lanes span all 64 entries -> in-wave reductions only
    float sv = sc[lane];
    float mx = sv;
#pragma unroll
    for (int o = 32; o > 0; o >>= 1) mx = fmaxf(mx, __shfl_xor(mx, o, 64));
    float e = expf(sv - mx);
    float sm = e;
#pragma unroll
    for (int o = 32; o > 0; o >>= 1) sm += __shfl_xor(sm, o, 64);
    if (t < CH) sc[t] = e;
    __syncthreads();

    // PV: wave-per-row, float4 per lane
    float4 a4 = make_float4(0.f, 0.f, 0.f, 0.f);
#pragma unroll 4
    for (int l = wave; l < CH; l += 4) {
        float4 vf = *(const float4*)(vp[l] + lane * 4);
        float pw = sc[l];
        a4.x = fmaf(pw, vf.x, a4.x);
        a4.y = fmaf(pw, vf.y, a4.y);
        a4.z = fmaf(pw, vf.z, a4.z);
        a4.w = fmaf(pw, vf.w, a4.w);
    }
    *(float4*)(&cx[wave][lane * 4]) = a4;
    __syncthreads();

    int pi = blockIdx.x * NCH + c;
    pctx[(size_t)pi * DD + t] = cx[0][t] + cx[1][t] + cx[2][t] + cx[3][t];
    if (t == 0) { pm[pi] = mx; pl[pi] = sm; }
}

// ---------------- attention combine: block = (b,h) ----------------
__global__ __launch_bounds__(256) void attn_comb_kernel(const float* __restrict__ pm,
    const float* __restrict__ pl, const float* __restrict__ pctx,
    float* __restrict__ ctxT)
{
    int bh = blockIdx.x;
    int b = bh >> 4, h = bh & 15;
    int t = threadIdx.x;
    float M = -INFINITY;
#pragma unroll
    for (int c = 0; c < NCH; ++c) M = fmaxf(M, pm[bh * NCH + c]);
    float L = 0.f, acc = 0.f;
#pragma unroll
    for (int c = 0; c < NCH; ++c) {
        float wv = expf(pm[bh * NCH + c] - M);
        L += pl[bh * NCH + c] * wv;
        acc += pctx[((size_t)bh * NCH + c) * DD + t] * wv;
    }
    ctxT[((size_t)h * DD + t) * BB + b] = acc / L;
}

extern "C" void kernel_launch(void* const* d_in, const int* in_sizes, int n_in,
                              void* d_out, int out_size, void* d_ws, size_t ws_size,
                              hipStream_t stream)
{
    (void)in_sizes; (void)n_in; (void)out_size; (void)ws_size;
    const float* hs      = (const float*)d_in[0];
    const float* kcache  = (const float*)d_in[1];
    const float* vcache  = (const float*)d_in[2];
    const float* ln_w    = (const float*)d_in[3];
    const float* ln_b    = (const float*)d_in[4];
    const float* wq      = (const float*)d_in[5];
    const float* wk      = (const float*)d_in[6];
    const float* wv      = (const float*)d_in[7];
    const float* wo      = (const float*)d_in[8];
    const float* fc_in_w = (const float*)d_in[9];
    const float* fc_in_b = (const float*)d_in[10];
    const float* fc_out_w= (const float*)d_in[11];
    const float* fc_out_b= (const float*)d_in[12];
    const float* mask    = (const float*)d_in[13];
    const int* nkl       = (const int*)d_in[14];
    const int* nvl       = (const int*)d_in[15];
    const int* kidx      = (const int*)d_in[16];
    const int* vidx      = (const int*)d_in[17];
    const int* pos       = (const int*)d_in[18];
    float* out = (float*)d_out;

    char* ws = (char*)d_ws;
    float* hT      = (float*)ws; ws += (size_t)NEMB * BB * 4;
    float* qb      = (float*)ws; ws += (size_t)BB * NEMB * 4;
    float* kb      = (float*)ws; ws += (size_t)BB * NEMB * 4;
    float* vb      = (float*)ws; ws += (size_t)BB * NEMB * 4;
    float* ctxT    = (float*)ws; ws += (size_t)NEMB * BB * 4;
    float* attn_o  = (float*)ws; ws += (size_t)BB * NEMB * 4;
    float* mT      = (float*)ws; ws += (size_t)NINT * BB * 4;
    float* pm      = (float*)ws; ws += (size_t)BB * HH * NCH * 4;
    float* pl      = (float*)ws; ws += (size_t)BB * HH * NCH * 4;
    float* pctx    = (float*)ws; ws += (size_t)BB * HH * NCH * DD * 4;
    float* Pq      = (float*)ws; ws += (size_t)3 * 32 * 32 * NEMB * 4;   // 50.3 MB
    float* P0      = (float*)ws; ws += (size_t)64 * 32 * NEMB * 4;       // 33.6 MB
    float* P1      = (float*)ws; ws += (size_t)16 * 32 * NINT * 4;       // 33.6 MB
    float* P2      = (float*)ws;                                          // 33.6 MB

    ln_kernel<<<BB, 256, 0, stream>>>(hs, ln_w, ln_b, hT);

    // QKV: S=32 chunk 128, 768 blocks
    gemm_qkv_kernel<<<dim3(8, 32, 3), 256, 0, stream>>>(hT, wq, wk, wv, Pq);
    qkv_rr_kernel<<<dim3(8, 32, 3), 256, 0, stream>>>(Pq, qb, kb, vb, pos);

    attn_part_kernel<<<dim3(BB * HH, NCH), 256, 0, stream>>>(qb, kb, vb, kcache, vcache,
                                                             kidx, vidx, nkl, nvl, mask,
                                                             pm, pl, pctx);
    attn_comb_kernel<<<BB * HH, 256, 0, stream>>>(pm, pl, pctx, ctxT);

    // Wo (512 blocks) + fc_in (512 blocks) in one launch
    gemm_dual_kernel<<<1024, 256, 0, stream>>>(ctxT, wo, P0, hT, fc_in_w, P1);
    reduce_dual_kernel<<<dim3(80, 32), 256, 0, stream>>>(P0, P1, fc_in_b, attn_o, mT);

    // fc_out: S=64 chunk 256, 512 blocks; fused bias + attn_out + residual
    gemm_fcout_kernel<<<dim3(8, 64), 256, 0, stream>>>(mT, fc_out_w, P2);
    reduce_final_kernel<<<dim3(16, 32), 256, 0, stream>>>(P2, fc_out_b, attn_o, hs, out);
}

// Round 5
// 513.901 us; speedup vs baseline: 2.2410x; 1.0544x over previous
//
#include <hip/hip_runtime.h>
#include <math.h>

#define BB 32
#define HH 16
#define DD 256
#define RDIM 64
#define NEMB 4096
#define NINT 16384
#define NSLOTS 32768
#define KVLEN 1024
#define LNEPS 1e-5f
#define NCH 16
#define CH 64

// ---------------- LayerNorm -> hT [NE][32] (A-transposed for GEMM) ----------------
__global__ __launch_bounds__(256) void ln_kernel(const float* __restrict__ x,
    const float* __restrict__ lw, const float* __restrict__ lb,
    float* __restrict__ hT)
{
    int b = blockIdx.x;
    int t = threadIdx.x;
    const float* row = x + (size_t)b * NEMB;
    float4 v[4];
    float sum = 0.f, sq = 0.f;
#pragma unroll
    for (int j = 0; j < 4; ++j) {
        v[j] = *(const float4*)(row + t * 4 + j * 1024);
        sum += v[j].x + v[j].y + v[j].z + v[j].w;
        sq += v[j].x * v[j].x + v[j].y * v[j].y + v[j].z * v[j].z + v[j].w * v[j].w;
    }
    __shared__ float s1[4], s2[4];
#pragma unroll
    for (int o = 32; o > 0; o >>= 1) {
        sum += __shfl_xor(sum, o, 64);
        sq += __shfl_xor(sq, o, 64);
    }
    int wave = t >> 6, lane = t & 63;
    if (lane == 0) { s1[wave] = sum; s2[wave] = sq; }
    __syncthreads();
    sum = s1[0] + s1[1] + s1[2] + s1[3];
    sq = s2[0] + s2[1] + s2[2] + s2[3];
    float mu = sum / NEMB;
    float var = sq / NEMB - mu * mu;
    float rstd = rsqrtf(var + LNEPS);
#pragma unroll
    for (int j = 0; j < 4; ++j) {
        int n = t * 4 + j * 1024;
        float4 wv = *(const float4*)(lw + n);
        float4 bv = *(const float4*)(lb + n);
        hT[(size_t)(n + 0) * BB + b] = (v[j].x - mu) * rstd * wv.x + bv.x;
        hT[(size_t)(n + 1) * BB + b] = (v[j].y - mu) * rstd * wv.y + bv.y;
        hT[(size_t)(n + 2) * BB + b] = (v[j].z - mu) * rstd * wv.z + bv.z;
        hT[(size_t)(n + 3) * BB + b] = (v[j].w - mu) * rstd * wv.w + bv.w;
    }
}

// ---------------- shared GEMM body: thread = 2n x 32m ----------------
__device__ __forceinline__ void gemm_body(const float* __restrict__ AT,
    const float* __restrict__ W, float* __restrict__ P,
    int N, int kChunk, int x, int s)
{
    int n = (x * 256 + threadIdx.x) * 2;
    size_t k0 = (size_t)s * kChunk;
    float2 acc[32];
#pragma unroll
    for (int mi = 0; mi < 32; ++mi) acc[mi] = make_float2(0.f, 0.f);
    const float* w = W + k0 * N + n;
    const float* a = AT + k0 * 32;   // wave-uniform, contiguous 128B per k
#pragma unroll 4
    for (int kk = 0; kk < kChunk; ++kk) {
        float2 wv = *(const float2*)w;
#pragma unroll
        for (int mi = 0; mi < 32; ++mi) {
            float am = a[mi];
            acc[mi].x = fmaf(am, wv.x, acc[mi].x);
            acc[mi].y = fmaf(am, wv.y, acc[mi].y);
        }
        w += N;
        a += 32;
    }
    float* p = P + ((size_t)s * 32) * N + n;
#pragma unroll
    for (int mi = 0; mi < 32; ++mi)
        *(float2*)(p + (size_t)mi * N) = acc[mi];
}

// ---- phase 2: QKV gemm (768 blocks) + fc_in gemm (512 blocks) ----
__global__ __launch_bounds__(256) void phase2_kernel(const float* __restrict__ hT,
    const float* __restrict__ wq, const float* __restrict__ wk, const float* __restrict__ wv,
    float* __restrict__ Pq, const float* __restrict__ fciw, float* __restrict__ P1)
{
    int id = blockIdx.x;
    if (id < 768) {
        int w = id >> 8;
        const float* W = (w == 0) ? wq : (w == 1) ? wk : wv;
        float* Pz = Pq + (size_t)w * ((size_t)32 * 32 * NEMB);
        gemm_body(hT, W, Pz, NEMB, 128, id & 7, (id >> 3) & 31);
    } else {
        id -= 768;
        gemm_body(hT, fciw, P1, NINT, 256, id & 31, id >> 5);
    }
}

__device__ inline float gelu_tanh(float x)
{
    float x3 = x * x * x;
    return 0.5f * x * (1.f + tanhf(0.7978845608028654f * (x + 0.044715f * x3)));
}

// ---- phase 3: QKV reduce+RoPE (768 blocks) + fc_in reduce+gelu (2048 blocks) ----
__global__ __launch_bounds__(256) void phase3_kernel(const float* __restrict__ Pq,
    float* __restrict__ q, float* __restrict__ k, float* __restrict__ v,
    const int* __restrict__ pos,
    const float* __restrict__ P1, const float* __restrict__ fcib, float* __restrict__ mT)
{
    int id = blockIdx.x, t = threadIdx.x;
    if (id < 768) {
        int w = id >> 8;
        int m = (id >> 3) & 31;
        int n0 = ((id & 7) * 256 + t) * 2;
        const float* p = Pq + (size_t)w * ((size_t)32 * 32 * NEMB) + (size_t)m * NEMB + n0;
        float sx = 0.f, sy = 0.f;
#pragma unroll 4
        for (int i = 0; i < 32; ++i) {
            float2 u = *(const float2*)p;
            sx += u.x; sy += u.y;
            p += (size_t)32 * NEMB;
        }
        int d = n0 & (DD - 1);
        if (w < 2 && d < RDIM) {
            int i = d >> 1;
            float fr = exp2f((float)i * (-13.287712379549449f / 32.f)); // 10000^(-i/32)
            float ang = (float)pos[m] * fr;
            float sn, cs;
            sincosf(ang, &sn, &cs);
            float x1 = sx, x2 = sy;
            sx = x1 * cs - x2 * sn;
            sy = x2 * cs + x1 * sn;
        }
        float* o = (w == 0) ? q : (w == 1) ? k : v;
        *(float2*)(o + (size_t)m * NEMB + n0) = make_float2(sx, sy);
    } else {
        int j = id - 768;
        int m = j >> 6;
        int n = (j & 63) * 256 + t;
        const float* p = P1 + (size_t)m * NINT + n;
        float s = 0.f;
#pragma unroll 4
        for (int i = 0; i < 16; ++i) { s += *p; p += (size_t)32 * NINT; }
        mT[(size_t)n * 32 + m] = gelu_tanh(s + fcib[n]);
    }
}

// ---- phase 4: attention partials (8192 blocks) + fc_out gemm (512 blocks) ----
__global__ __launch_bounds__(256) void phase4_kernel(const float* __restrict__ q,
    const float* __restrict__ knew, const float* __restrict__ vnew,
    const float* __restrict__ kcache, const float* __restrict__ vcache,
    const int* __restrict__ kidx, const int* __restrict__ vidx,
    const int* __restrict__ nkl, const int* __restrict__ nvl,
    const float* __restrict__ mask,
    float* __restrict__ pm, float* __restrict__ pl, float* __restrict__ pctx,
    const float* __restrict__ mT, const float* __restrict__ fcow, float* __restrict__ P2)
{
    int id = blockIdx.x;
    if (id >= 8192) {
        int j = id - 8192;
        gemm_body(mT, fcow, P2, NEMB, 256, j & 7, j >> 3);
        return;
    }
    int bh = id >> 4, c = id & 15;
    int b = bh >> 4, h = bh & 15;
    int t = threadIdx.x;
    __shared__ float qs[DD];
    __shared__ float sc[CH];
    __shared__ const float* kp[CH];
    __shared__ const float* vp[CH];
    __shared__ float cx[4][DD];

    qs[t] = q[(size_t)b * NEMB + (size_t)h * DD + t];
    if (t < CH) {
        int l = c * CH + t;
        int ks = kidx[b * KVLEN + l];
        int vs = vidx[b * KVLEN + l];
        const float* kbase = kcache + (size_t)ks * NEMB;
        const float* vbase = vcache + (size_t)vs * NEMB;
#pragma unroll
        for (int j = 0; j < BB; ++j) {
            if (nkl[j] == ks) kbase = knew + (size_t)j * NEMB;
            if (nvl[j] == vs) vbase = vnew + (size_t)j * NEMB;
        }
        kp[t] = kbase + (size_t)h * DD;
        vp[t] = vbase + (size_t)h * DD;
    }
    __syncthreads();

    int wave = t >> 6, lane = t & 63;
    float4 qf = *(const float4*)(qs + lane * 4);
#pragma unroll 4
    for (int l = wave; l < CH; l += 4) {
        const float4 kf = *(const float4*)(kp[l] + lane * 4);
        float d = fmaf(kf.x, qf.x, fmaf(kf.y, qf.y, fmaf(kf.z, qf.z, kf.w * qf.w)));
#pragma unroll
        for (int o = 32; o > 0; o >>= 1) d += __shfl_xor(d, o, 64);
        if (lane == 0) sc[l] = d * 0.0625f + mask[b * KVLEN + c * CH + l];
    }
    __syncthreads();

    float sv = sc[lane];
    float mx = sv;
#pragma unroll
    for (int o = 32; o > 0; o >>= 1) mx = fmaxf(mx, __shfl_xor(mx, o, 64));
    float e = expf(sv - mx);
    float sm = e;
#pragma unroll
    for (int o = 32; o > 0; o >>= 1) sm += __shfl_xor(sm, o, 64);
    if (t < CH) sc[t] = e;
    __syncthreads();

    float4 a4 = make_float4(0.f, 0.f, 0.f, 0.f);
#pragma unroll 4
    for (int l = wave; l < CH; l += 4) {
        float4 vf = *(const float4*)(vp[l] + lane * 4);
        float pw = sc[l];
        a4.x = fmaf(pw, vf.x, a4.x);
        a4.y = fmaf(pw, vf.y, a4.y);
        a4.z = fmaf(pw, vf.z, a4.z);
        a4.w = fmaf(pw, vf.w, a4.w);
    }
    *(float4*)(&cx[wave][lane * 4]) = a4;
    __syncthreads();

    int pi = bh * NCH + c;
    pctx[(size_t)pi * DD + t] = cx[0][t] + cx[1][t] + cx[2][t] + cx[3][t];
    if (t == 0) { pm[pi] = mx; pl[pi] = sm; }
}

// ---- phase 5: attention combine (512 blocks) ----
__global__ __launch_bounds__(256) void attn_comb_kernel(const float* __restrict__ pm,
    const float* __restrict__ pl, const float* __restrict__ pctx,
    float* __restrict__ ctxT)
{
    int bh = blockIdx.x;
    int b = bh >> 4, h = bh & 15;
    int t = threadIdx.x;
    float M = -INFINITY;
#pragma unroll
    for (int c = 0; c < NCH; ++c) M = fmaxf(M, pm[bh * NCH + c]);
    float L = 0.f, acc = 0.f;
#pragma unroll
    for (int c = 0; c < NCH; ++c) {
        float wv = expf(pm[bh * NCH + c] - M);
        L += pl[bh * NCH + c] * wv;
        acc += pctx[((size_t)bh * NCH + c) * DD + t] * wv;
    }
    ctxT[((size_t)h * DD + t) * BB + b] = acc / L;
}

// ---- phase 6: Wo gemm (512 blocks) + fc_out reduce -> mlp_tmp (512 blocks) ----
__global__ __launch_bounds__(256) void phase6_kernel(const float* __restrict__ ctxT,
    const float* __restrict__ wo, float* __restrict__ P0,
    const float* __restrict__ P2, const float* __restrict__ fcob,
    const float* __restrict__ resid, float* __restrict__ mlp_tmp)
{
    int id = blockIdx.x, t = threadIdx.x;
    if (id < 512) {
        gemm_body(ctxT, wo, P0, NEMB, 64, id & 7, id >> 3);
    } else {
        int j = id - 512;
        int m = j >> 4;
        int n = (j & 15) * 256 + t;
        const float* p = P2 + (size_t)m * NEMB + n;
        float s = 0.f;
#pragma unroll 4
        for (int i = 0; i < 64; ++i) { s += *p; p += (size_t)32 * NEMB; }
        mlp_tmp[(size_t)m * NEMB + n] = s + fcob[n] + resid[(size_t)m * NEMB + n];
    }
}

// ---- phase 7: Wo reduce + mlp_tmp -> out (512 blocks) ----
__global__ __launch_bounds__(256) void phase7_kernel(const float* __restrict__ P0,
    const float* __restrict__ mlp_tmp, float* __restrict__ out)
{
    int n = blockIdx.x * 256 + threadIdx.x;
    int m = blockIdx.y;
    const float* p = P0 + (size_t)m * NEMB + n;
    float s = 0.f;
#pragma unroll 4
    for (int i = 0; i < 64; ++i) { s += *p; p += (size_t)32 * NEMB; }
    out[(size_t)m * NEMB + n] = s + mlp_tmp[(size_t)m * NEMB + n];
}

extern "C" void kernel_launch(void* const* d_in, const int* in_sizes, int n_in,
                              void* d_out, int out_size, void* d_ws, size_t ws_size,
                              hipStream_t stream)
{
    (void)in_sizes; (void)n_in; (void)out_size; (void)ws_size;
    const float* hs      = (const float*)d_in[0];
    const float* kcache  = (const float*)d_in[1];
    const float* vcache  = (const float*)d_in[2];
    const float* ln_w    = (const float*)d_in[3];
    const float* ln_b    = (const float*)d_in[4];
    const float* wq      = (const float*)d_in[5];
    const float* wk      = (const float*)d_in[6];
    const float* wv      = (const float*)d_in[7];
    const float* wo      = (const float*)d_in[8];
    const float* fc_in_w = (const float*)d_in[9];
    const float* fc_in_b = (const float*)d_in[10];
    const float* fc_out_w= (const float*)d_in[11];
    const float* fc_out_b= (const float*)d_in[12];
    const float* mask    = (const float*)d_in[13];
    const int* nkl       = (const int*)d_in[14];
    const int* nvl       = (const int*)d_in[15];
    const int* kidx      = (const int*)d_in[16];
    const int* vidx      = (const int*)d_in[17];
    const int* pos       = (const int*)d_in[18];
    float* out = (float*)d_out;

    char* ws = (char*)d_ws;
    float* hT      = (float*)ws; ws += (size_t)NEMB * BB * 4;
    float* qb      = (float*)ws; ws += (size_t)BB * NEMB * 4;
    float* kb      = (float*)ws; ws += (size_t)BB * NEMB * 4;
    float* vb      = (float*)ws; ws += (size_t)BB * NEMB * 4;
    float* ctxT    = (float*)ws; ws += (size_t)NEMB * BB * 4;
    float* mlp_tmp = (float*)ws; ws += (size_t)BB * NEMB * 4;
    float* mT      = (float*)ws; ws += (size_t)NINT * BB * 4;
    float* pm      = (float*)ws; ws += (size_t)BB * HH * NCH * 4;
    float* pl      = (float*)ws; ws += (size_t)BB * HH * NCH * 4;
    float* pctx    = (float*)ws; ws += (size_t)BB * HH * NCH * DD * 4;
    float* Pq      = (float*)ws; ws += (size_t)3 * 32 * 32 * NEMB * 4;   // 50.3 MB
    float* P0      = (float*)ws; ws += (size_t)64 * 32 * NEMB * 4;       // 33.6 MB
    float* P1      = (float*)ws; ws += (size_t)16 * 32 * NINT * 4;       // 33.6 MB
    float* P2      = (float*)ws;                                          // 33.6 MB

    ln_kernel<<<BB, 256, 0, stream>>>(hs, ln_w, ln_b, hT);

    phase2_kernel<<<1280, 256, 0, stream>>>(hT, wq, wk, wv, Pq, fc_in_w, P1);

    phase3_kernel<<<2816, 256, 0, stream>>>(Pq, qb, kb, vb, pos, P1, fc_in_b, mT);

    phase4_kernel<<<8704, 256, 0, stream>>>(qb, kb, vb, kcache, vcache,
                                            kidx, vidx, nkl, nvl, mask,
                                            pm, pl, pctx, mT, fc_out_w, P2);

    attn_comb_kernel<<<BB * HH, 256, 0, stream>>>(pm, pl, pctx, ctxT);

    phase6_kernel<<<1024, 256, 0, stream>>>(ctxT, wo, P0, P2, fc_out_b, hs, mlp_tmp);

    phase7_kernel<<<dim3(16, 32), 256, 0, stream>>>(P0, mlp_tmp, out);
}

// Round 6
// 503.470 us; speedup vs baseline: 2.2874x; 1.0207x over previous
//
#include <hip/hip_runtime.h>
#include <math.h>

#define BB 32
#define HH 16
#define DD 256
#define RDIM 64
#define NEMB 4096
#define NINT 16384
#define NSLOTS 32768
#define KVLEN 1024
#define LNEPS 1e-5f
#define NCH 16
#define CH 64

// ---------------- LayerNorm -> hT [NE][32] (A-transposed for GEMM) ----------------
__global__ __launch_bounds__(256) void ln_kernel(const float* __restrict__ x,
    const float* __restrict__ lw, const float* __restrict__ lb,
    float* __restrict__ hT)
{
    int b = blockIdx.x;
    int t = threadIdx.x;
    const float* row = x + (size_t)b * NEMB;
    float4 v[4];
    float sum = 0.f, sq = 0.f;
#pragma unroll
    for (int j = 0; j < 4; ++j) {
        v[j] = *(const float4*)(row + t * 4 + j * 1024);
        sum += v[j].x + v[j].y + v[j].z + v[j].w;
        sq += v[j].x * v[j].x + v[j].y * v[j].y + v[j].z * v[j].z + v[j].w * v[j].w;
    }
    __shared__ float s1[4], s2[4];
#pragma unroll
    for (int o = 32; o > 0; o >>= 1) {
        sum += __shfl_xor(sum, o, 64);
        sq += __shfl_xor(sq, o, 64);
    }
    int wave = t >> 6, lane = t & 63;
    if (lane == 0) { s1[wave] = sum; s2[wave] = sq; }
    __syncthreads();
    sum = s1[0] + s1[1] + s1[2] + s1[3];
    sq = s2[0] + s2[1] + s2[2] + s2[3];
    float mu = sum / NEMB;
    float var = sq / NEMB - mu * mu;
    float rstd = rsqrtf(var + LNEPS);
#pragma unroll
    for (int j = 0; j < 4; ++j) {
        int n = t * 4 + j * 1024;
        float4 wv = *(const float4*)(lw + n);
        float4 bv = *(const float4*)(lb + n);
        hT[(size_t)(n + 0) * BB + b] = (v[j].x - mu) * rstd * wv.x + bv.x;
        hT[(size_t)(n + 1) * BB + b] = (v[j].y - mu) * rstd * wv.y + bv.y;
        hT[(size_t)(n + 2) * BB + b] = (v[j].z - mu) * rstd * wv.z + bv.z;
        hT[(size_t)(n + 3) * BB + b] = (v[j].w - mu) * rstd * wv.w + bv.w;
    }
}

// ---------------- shared GEMM body: thread = 2n x 32m ----------------
__device__ __forceinline__ void gemm_body(const float* __restrict__ AT,
    const float* __restrict__ W, float* __restrict__ P,
    int N, int kChunk, int x, int s)
{
    int n = (x * 256 + threadIdx.x) * 2;
    size_t k0 = (size_t)s * kChunk;
    float2 acc[32];
#pragma unroll
    for (int mi = 0; mi < 32; ++mi) acc[mi] = make_float2(0.f, 0.f);
    const float* w = W + k0 * N + n;
    const float* a = AT + k0 * 32;   // wave-uniform, contiguous 128B per k
#pragma unroll 4
    for (int kk = 0; kk < kChunk; ++kk) {
        float2 wv = *(const float2*)w;
#pragma unroll
        for (int mi = 0; mi < 32; ++mi) {
            float am = a[mi];
            acc[mi].x = fmaf(am, wv.x, acc[mi].x);
            acc[mi].y = fmaf(am, wv.y, acc[mi].y);
        }
        w += N;
        a += 32;
    }
    float* p = P + ((size_t)s * 32) * N + n;
#pragma unroll
    for (int mi = 0; mi < 32; ++mi)
        *(float2*)(p + (size_t)mi * N) = acc[mi];
}

// ---- phase 2: QKV gemm (768 blocks) + fc_in gemm (512 blocks) ----
__global__ __launch_bounds__(256) void phase2_kernel(const float* __restrict__ hT,
    const float* __restrict__ wq, const float* __restrict__ wk, const float* __restrict__ wv,
    float* __restrict__ Pq, const float* __restrict__ fciw, float* __restrict__ P1)
{
    int id = blockIdx.x;
    if (id < 768) {
        int w = id >> 8;
        const float* W = (w == 0) ? wq : (w == 1) ? wk : wv;
        float* Pz = Pq + (size_t)w * ((size_t)32 * 32 * NEMB);
        gemm_body(hT, W, Pz, NEMB, 128, id & 7, (id >> 3) & 31);
    } else {
        id -= 768;
        gemm_body(hT, fciw, P1, NINT, 256, id & 31, id >> 5);
    }
}

__device__ inline float gelu_tanh(float x)
{
    float x3 = x * x * x;
    return 0.5f * x * (1.f + tanhf(0.7978845608028654f * (x + 0.044715f * x3)));
}

// ---- phase 3: QKV reduce+RoPE (768 blocks) + fc_in reduce+gelu (2048 blocks) ----
__global__ __launch_bounds__(256) void phase3_kernel(const float* __restrict__ Pq,
    float* __restrict__ q, float* __restrict__ k, float* __restrict__ v,
    const int* __restrict__ pos,
    const float* __restrict__ P1, const float* __restrict__ fcib, float* __restrict__ mT)
{
    int id = blockIdx.x, t = threadIdx.x;
    if (id < 768) {
        int w = id >> 8;
        int m = (id >> 3) & 31;
        int n0 = ((id & 7) * 256 + t) * 2;
        const float* p = Pq + (size_t)w * ((size_t)32 * 32 * NEMB) + (size_t)m * NEMB + n0;
        float sx = 0.f, sy = 0.f;
#pragma unroll 4
        for (int i = 0; i < 32; ++i) {
            float2 u = *(const float2*)p;
            sx += u.x; sy += u.y;
            p += (size_t)32 * NEMB;
        }
        int d = n0 & (DD - 1);
        if (w < 2 && d < RDIM) {
            int i = d >> 1;
            float fr = exp2f((float)i * (-13.287712379549449f / 32.f)); // 10000^(-i/32)
            float ang = (float)pos[m] * fr;
            float sn, cs;
            sincosf(ang, &sn, &cs);
            float x1 = sx, x2 = sy;
            sx = x1 * cs - x2 * sn;
            sy = x2 * cs + x1 * sn;
        }
        float* o = (w == 0) ? q : (w == 1) ? k : v;
        *(float2*)(o + (size_t)m * NEMB + n0) = make_float2(sx, sy);
    } else {
        int j = id - 768;
        int m = j >> 6;
        int n = (j & 63) * 256 + t;
        const float* p = P1 + (size_t)m * NINT + n;
        float s = 0.f;
#pragma unroll 4
        for (int i = 0; i < 16; ++i) { s += *p; p += (size_t)32 * NINT; }
        mT[(size_t)n * 32 + m] = gelu_tanh(s + fcib[n]);
    }
}

// ---- phase 4: attention partials (8192 blocks) + fc_out gemm (512 blocks) ----
__global__ __launch_bounds__(256) void phase4_kernel(const float* __restrict__ q,
    const float* __restrict__ knew, const float* __restrict__ vnew,
    const float* __restrict__ kcache, const float* __restrict__ vcache,
    const int* __restrict__ kidx, const int* __restrict__ vidx,
    const int* __restrict__ nkl, const int* __restrict__ nvl,
    const float* __restrict__ mask,
    float* __restrict__ pm, float* __restrict__ pl, float* __restrict__ pctx,
    const float* __restrict__ mT, const float* __restrict__ fcow, float* __restrict__ P2)
{
    int id = blockIdx.x;
    if (id >= 8192) {
        int j = id - 8192;
        gemm_body(mT, fcow, P2, NEMB, 256, j & 7, j >> 3);
        return;
    }
    int bh = id >> 4, c = id & 15;
    int b = bh >> 4, h = bh & 15;
    int t = threadIdx.x;
    __shared__ float qs[DD];
    __shared__ float sc[CH];
    __shared__ const float* kp[CH];
    __shared__ const float* vp[CH];
    __shared__ float cx[4][DD];

    qs[t] = q[(size_t)b * NEMB + (size_t)h * DD + t];
    if (t < CH) {
        int l = c * CH + t;
        int ks = kidx[b * KVLEN + l];
        int vs = vidx[b * KVLEN + l];
        const float* kbase = kcache + (size_t)ks * NEMB;
        const float* vbase = vcache + (size_t)vs * NEMB;
#pragma unroll
        for (int j = 0; j < BB; ++j) {
            if (nkl[j] == ks) kbase = knew + (size_t)j * NEMB;
            if (nvl[j] == vs) vbase = vnew + (size_t)j * NEMB;
        }
        kp[t] = kbase + (size_t)h * DD;
        vp[t] = vbase + (size_t)h * DD;
    }
    __syncthreads();

    int wave = t >> 6, lane = t & 63;
    int g = lane >> 4, u = lane & 15;    // 16-lane group; lane covers d = u*4 + j*64

    // q fragment in registers
    float4 qf[4];
#pragma unroll
    for (int j = 0; j < 4; ++j) qf[j] = *(const float4*)(qs + u * 4 + j * 64);

    // QK: wave handles 16 rows, 4 at a time (one per group); 4-shuffle reduce within 16 lanes
#pragma unroll
    for (int it = 0; it < 4; ++it) {
        int l = it * 16 + wave * 4 + g;
        const float* kr = kp[l];
        float d = 0.f;
#pragma unroll
        for (int j = 0; j < 4; ++j) {
            float4 kf = *(const float4*)(kr + u * 4 + j * 64);
            d = fmaf(kf.x, qf[j].x, fmaf(kf.y, qf[j].y, fmaf(kf.z, qf[j].z, fmaf(kf.w, qf[j].w, d))));
        }
        d += __shfl_xor(d, 8, 64);
        d += __shfl_xor(d, 4, 64);
        d += __shfl_xor(d, 2, 64);
        d += __shfl_xor(d, 1, 64);
        if (u == 0) sc[l] = d * 0.0625f + mask[b * KVLEN + c * CH + l];
    }
    __syncthreads();

    // softmax stats: every wave holds all 64 rows in its lanes
    float sv = sc[lane];
    float mx = sv;
#pragma unroll
    for (int o = 32; o > 0; o >>= 1) mx = fmaxf(mx, __shfl_xor(mx, o, 64));
    float e = expf(sv - mx);
    float sm = e;
#pragma unroll
    for (int o = 32; o > 0; o >>= 1) sm += __shfl_xor(sm, o, 64);

    // PV: no barrier needed — weights broadcast from lanes via shfl
    float4 a4 = make_float4(0.f, 0.f, 0.f, 0.f);
#pragma unroll 8
    for (int l = wave; l < CH; l += 4) {
        float4 vf = *(const float4*)(vp[l] + lane * 4);
        float pw = __shfl(e, l, 64);
        a4.x = fmaf(pw, vf.x, a4.x);
        a4.y = fmaf(pw, vf.y, a4.y);
        a4.z = fmaf(pw, vf.z, a4.z);
        a4.w = fmaf(pw, vf.w, a4.w);
    }
    *(float4*)(&cx[wave][lane * 4]) = a4;
    __syncthreads();

    int pi = bh * NCH + c;
    pctx[(size_t)pi * DD + t] = cx[0][t] + cx[1][t] + cx[2][t] + cx[3][t];
    if (t == 0) { pm[pi] = mx; pl[pi] = sm; }
}

// ---- phase 5: attention combine (512 blocks) ----
__global__ __launch_bounds__(256) void attn_comb_kernel(const float* __restrict__ pm,
    const float* __restrict__ pl, const float* __restrict__ pctx,
    float* __restrict__ ctxT)
{
    int bh = blockIdx.x;
    int b = bh >> 4, h = bh & 15;
    int t = threadIdx.x;
    float M = -INFINITY;
#pragma unroll
    for (int c = 0; c < NCH; ++c) M = fmaxf(M, pm[bh * NCH + c]);
    float L = 0.f, acc = 0.f;
#pragma unroll
    for (int c = 0; c < NCH; ++c) {
        float wv = expf(pm[bh * NCH + c] - M);
        L += pl[bh * NCH + c] * wv;
        acc += pctx[((size_t)bh * NCH + c) * DD + t] * wv;
    }
    ctxT[((size_t)h * DD + t) * BB + b] = acc / L;
}

// ---- phase 6: Wo gemm (512 blocks) + fc_out reduce -> mlp_tmp (512 blocks) ----
__global__ __launch_bounds__(256) void phase6_kernel(const float* __restrict__ ctxT,
    const float* __restrict__ wo, float* __restrict__ P0,
    const float* __restrict__ P2, const float* __restrict__ fcob,
    const float* __restrict__ resid, float* __restrict__ mlp_tmp)
{
    int id = blockIdx.x, t = threadIdx.x;
    if (id < 512) {
        gemm_body(ctxT, wo, P0, NEMB, 64, id & 7, id >> 3);
    } else {
        int j = id - 512;
        int m = j >> 4;
        int n = (j & 15) * 256 + t;
        const float* p = P2 + (size_t)m * NEMB + n;
        float s = 0.f;
#pragma unroll 4
        for (int i = 0; i < 64; ++i) { s += *p; p += (size_t)32 * NEMB; }
        mlp_tmp[(size_t)m * NEMB + n] = s + fcob[n] + resid[(size_t)m * NEMB + n];
    }
}

// ---- phase 7: Wo reduce + mlp_tmp -> out (512 blocks) ----
__global__ __launch_bounds__(256) void phase7_kernel(const float* __restrict__ P0,
    const float* __restrict__ mlp_tmp, float* __restrict__ out)
{
    int n = blockIdx.x * 256 + threadIdx.x;
    int m = blockIdx.y;
    const float* p = P0 + (size_t)m * NEMB + n;
    float s = 0.f;
#pragma unroll 4
    for (int i = 0; i < 64; ++i) { s += *p; p += (size_t)32 * NEMB; }
    out[(size_t)m * NEMB + n] = s + mlp_tmp[(size_t)m * NEMB + n];
}

extern "C" void kernel_launch(void* const* d_in, const int* in_sizes, int n_in,
                              void* d_out, int out_size, void* d_ws, size_t ws_size,
                              hipStream_t stream)
{
    (void)in_sizes; (void)n_in; (void)out_size; (void)ws_size;
    const float* hs      = (const float*)d_in[0];
    const float* kcache  = (const float*)d_in[1];
    const float* vcache  = (const float*)d_in[2];
    const float* ln_w    = (const float*)d_in[3];
    const float* ln_b    = (const float*)d_in[4];
    const float* wq      = (const float*)d_in[5];
    const float* wk      = (const float*)d_in[6];
    const float* wv      = (const float*)d_in[7];
    const float* wo      = (const float*)d_in[8];
    const float* fc_in_w = (const float*)d_in[9];
    const float* fc_in_b = (const float*)d_in[10];
    const float* fc_out_w= (const float*)d_in[11];
    const float* fc_out_b= (const float*)d_in[12];
    const float* mask    = (const float*)d_in[13];
    const int* nkl       = (const int*)d_in[14];
    const int* nvl       = (const int*)d_in[15];
    const int* kidx      = (const int*)d_in[16];
    const int* vidx      = (const int*)d_in[17];
    const int* pos       = (const int*)d_in[18];
    float* out = (float*)d_out;

    char* ws = (char*)d_ws;
    float* hT      = (float*)ws; ws += (size_t)NEMB * BB * 4;
    float* qb      = (float*)ws; ws += (size_t)BB * NEMB * 4;
    float* kb      = (float*)ws; ws += (size_t)BB * NEMB * 4;
    float* vb      = (float*)ws; ws += (size_t)BB * NEMB * 4;
    float* ctxT    = (float*)ws; ws += (size_t)NEMB * BB * 4;
    float* mlp_tmp = (float*)ws; ws += (size_t)BB * NEMB * 4;
    float* mT      = (float*)ws; ws += (size_t)NINT * BB * 4;
    float* pm      = (float*)ws; ws += (size_t)BB * HH * NCH * 4;
    float* pl      = (float*)ws; ws += (size_t)BB * HH * NCH * 4;
    float* pctx    = (float*)ws; ws += (size_t)BB * HH * NCH * DD * 4;
    float* Pq      = (float*)ws; ws += (size_t)3 * 32 * 32 * NEMB * 4;   // 50.3 MB
    float* P0      = (float*)ws; ws += (size_t)64 * 32 * NEMB * 4;       // 33.6 MB
    float* P1      = (float*)ws; ws += (size_t)16 * 32 * NINT * 4;       // 33.6 MB
    float* P2      = (float*)ws;                                          // 33.6 MB

    ln_kernel<<<BB, 256, 0, stream>>>(hs, ln_w, ln_b, hT);

    phase2_kernel<<<1280, 256, 0, stream>>>(hT, wq, wk, wv, Pq, fc_in_w, P1);

    phase3_kernel<<<2816, 256, 0, stream>>>(Pq, qb, kb, vb, pos, P1, fc_in_b, mT);

    phase4_kernel<<<8704, 256, 0, stream>>>(qb, kb, vb, kcache, vcache,
                                            kidx, vidx, nkl, nvl, mask,
                                            pm, pl, pctx, mT, fc_out_w, P2);

    attn_comb_kernel<<<BB * HH, 256, 0, stream>>>(pm, pl, pctx, ctxT);

    phase6_kernel<<<1024, 256, 0, stream>>>(ctxT, wo, P0, P2, fc_out_b, hs, mlp_tmp);

    phase7_kernel<<<dim3(16, 32), 256, 0, stream>>>(P0, mlp_tmp, out);
}

// Round 7
// 448.016 us; speedup vs baseline: 2.5705x; 1.1238x over previous
//
#include <hip/hip_runtime.h>
#include <math.h>

#define BB 32
#define HH 16
#define DD 256
#define RDIM 64
#define NEMB 4096
#define NINT 16384
#define NSLOTS 32768
#define KVLEN 1024
#define LNEPS 1e-5f
#define NCH 16
#define CH 64

// ---------------- LayerNorm -> hT [NE][32] (A-transposed for GEMM) ----------------
__global__ __launch_bounds__(256) void ln_kernel(const float* __restrict__ x,
    const float* __restrict__ lw, const float* __restrict__ lb,
    float* __restrict__ hT)
{
    int b = blockIdx.x;
    int t = threadIdx.x;
    const float* row = x + (size_t)b * NEMB;
    float4 v[4];
    float sum = 0.f, sq = 0.f;
#pragma unroll
    for (int j = 0; j < 4; ++j) {
        v[j] = *(const float4*)(row + t * 4 + j * 1024);
        sum += v[j].x + v[j].y + v[j].z + v[j].w;
        sq += v[j].x * v[j].x + v[j].y * v[j].y + v[j].z * v[j].z + v[j].w * v[j].w;
    }
    __shared__ float s1[4], s2[4];
#pragma unroll
    for (int o = 32; o > 0; o >>= 1) {
        sum += __shfl_xor(sum, o, 64);
        sq += __shfl_xor(sq, o, 64);
    }
    int wave = t >> 6, lane = t & 63;
    if (lane == 0) { s1[wave] = sum; s2[wave] = sq; }
    __syncthreads();
    sum = s1[0] + s1[1] + s1[2] + s1[3];
    sq = s2[0] + s2[1] + s2[2] + s2[3];
    float mu = sum / NEMB;
    float var = sq / NEMB - mu * mu;
    float rstd = rsqrtf(var + LNEPS);
#pragma unroll
    for (int j = 0; j < 4; ++j) {
        int n = t * 4 + j * 1024;
        float4 wv = *(const float4*)(lw + n);
        float4 bv = *(const float4*)(lb + n);
        hT[(size_t)(n + 0) * BB + b] = (v[j].x - mu) * rstd * wv.x + bv.x;
        hT[(size_t)(n + 1) * BB + b] = (v[j].y - mu) * rstd * wv.y + bv.y;
        hT[(size_t)(n + 2) * BB + b] = (v[j].z - mu) * rstd * wv.z + bv.z;
        hT[(size_t)(n + 3) * BB + b] = (v[j].w - mu) * rstd * wv.w + bv.w;
    }
}

// ---------------- shared GEMM body (256 threads): thread = 2n x 32m ----------------
__device__ __forceinline__ void gemm_body(const float* __restrict__ AT,
    const float* __restrict__ W, float* __restrict__ P,
    int N, int kChunk, int x, int s)
{
    int n = (x * 256 + threadIdx.x) * 2;
    size_t k0 = (size_t)s * kChunk;
    float2 acc[32];
#pragma unroll
    for (int mi = 0; mi < 32; ++mi) acc[mi] = make_float2(0.f, 0.f);
    const float* w = W + k0 * N + n;
    const float* a = AT + k0 * 32;   // wave-uniform, contiguous 128B per k
#pragma unroll 4
    for (int kk = 0; kk < kChunk; ++kk) {
        float2 wv = *(const float2*)w;
#pragma unroll
        for (int mi = 0; mi < 32; ++mi) {
            float am = a[mi];
            acc[mi].x = fmaf(am, wv.x, acc[mi].x);
            acc[mi].y = fmaf(am, wv.y, acc[mi].y);
        }
        w += N;
        a += 32;
    }
    float* p = P + ((size_t)s * 32) * N + n;
#pragma unroll
    for (int mi = 0; mi < 32; ++mi)
        *(float2*)(p + (size_t)mi * N) = acc[mi];
}

// ---------------- 64-thread GEMM body: thread = 2n x 32m ----------------
__device__ __forceinline__ void gemm_body64(const float* __restrict__ AT,
    const float* __restrict__ W, float* __restrict__ P,
    int N, int kChunk, int x, int s)
{
    int n = (x * 64 + threadIdx.x) * 2;
    size_t k0 = (size_t)s * kChunk;
    float2 acc[32];
#pragma unroll
    for (int mi = 0; mi < 32; ++mi) acc[mi] = make_float2(0.f, 0.f);
    const float* w = W + k0 * N + n;
    const float* a = AT + k0 * 32;
#pragma unroll 4
    for (int kk = 0; kk < kChunk; ++kk) {
        float2 wv = *(const float2*)w;
#pragma unroll
        for (int mi = 0; mi < 32; ++mi) {
            float am = a[mi];
            acc[mi].x = fmaf(am, wv.x, acc[mi].x);
            acc[mi].y = fmaf(am, wv.y, acc[mi].y);
        }
        w += N;
        a += 32;
    }
    float* p = P + ((size_t)s * 32) * N + n;
#pragma unroll
    for (int mi = 0; mi < 32; ++mi)
        *(float2*)(p + (size_t)mi * N) = acc[mi];
}

// ---- phase 2: QKV gemm (768 blocks) + fc_in gemm (512 blocks) ----
__global__ __launch_bounds__(256) void phase2_kernel(const float* __restrict__ hT,
    const float* __restrict__ wq, const float* __restrict__ wk, const float* __restrict__ wv,
    float* __restrict__ Pq, const float* __restrict__ fciw, float* __restrict__ P1)
{
    int id = blockIdx.x;
    if (id < 768) {
        int w = id >> 8;
        const float* W = (w == 0) ? wq : (w == 1) ? wk : wv;
        float* Pz = Pq + (size_t)w * ((size_t)32 * 32 * NEMB);
        gemm_body(hT, W, Pz, NEMB, 128, id & 7, (id >> 3) & 31);
    } else {
        id -= 768;
        gemm_body(hT, fciw, P1, NINT, 256, id & 31, id >> 5);
    }
}

__device__ inline float gelu_tanh(float x)
{
    float x3 = x * x * x;
    return 0.5f * x * (1.f + tanhf(0.7978845608028654f * (x + 0.044715f * x3)));
}

// ---- phase 3: QKV reduce+RoPE (768 blocks) + fc_in reduce+gelu (2048 blocks) ----
__global__ __launch_bounds__(256) void phase3_kernel(const float* __restrict__ Pq,
    float* __restrict__ q, float* __restrict__ k, float* __restrict__ v,
    const int* __restrict__ pos,
    const float* __restrict__ P1, const float* __restrict__ fcib, float* __restrict__ mT)
{
    int id = blockIdx.x, t = threadIdx.x;
    if (id < 768) {
        int w = id >> 8;
        int m = (id >> 3) & 31;
        int n0 = ((id & 7) * 256 + t) * 2;
        const float* p = Pq + (size_t)w * ((size_t)32 * 32 * NEMB) + (size_t)m * NEMB + n0;
        float sx = 0.f, sy = 0.f;
#pragma unroll 4
        for (int i = 0; i < 32; ++i) {
            float2 u = *(const float2*)p;
            sx += u.x; sy += u.y;
            p += (size_t)32 * NEMB;
        }
        int d = n0 & (DD - 1);
        if (w < 2 && d < RDIM) {
            int i = d >> 1;
            float fr = exp2f((float)i * (-13.287712379549449f / 32.f)); // 10000^(-i/32)
            float ang = (float)pos[m] * fr;
            float sn, cs;
            sincosf(ang, &sn, &cs);
            float x1 = sx, x2 = sy;
            sx = x1 * cs - x2 * sn;
            sy = x2 * cs + x1 * sn;
        }
        float* o = (w == 0) ? q : (w == 1) ? k : v;
        *(float2*)(o + (size_t)m * NEMB + n0) = make_float2(sx, sy);
    } else {
        int j = id - 768;
        int m = j >> 6;
        int n = (j & 63) * 256 + t;
        const float* p = P1 + (size_t)m * NINT + n;
        float s = 0.f;
#pragma unroll 4
        for (int i = 0; i < 16; ++i) { s += *p; p += (size_t)32 * NINT; }
        mT[(size_t)n * 32 + m] = gelu_tanh(s + fcib[n]);
    }
}

// ---- phase 4: fc_out gemm (2048 blocks, FIRST) + attention partials (8192 1-wave blocks) ----
__global__ __launch_bounds__(64) void phase4_kernel(const float* __restrict__ q,
    const float* __restrict__ knew, const float* __restrict__ vnew,
    const float* __restrict__ kcache, const float* __restrict__ vcache,
    const int* __restrict__ kidx, const int* __restrict__ vidx,
    const int* __restrict__ nkl, const int* __restrict__ nvl,
    const float* __restrict__ mask,
    float* __restrict__ pm, float* __restrict__ pl, float* __restrict__ pctx,
    const float* __restrict__ mT, const float* __restrict__ fcow, float* __restrict__ P2)
{
    int id = blockIdx.x;
    int t = threadIdx.x;
    if (id < 2048) {
        // fc_out: N=4096, K=16384; x in [0,32), s in [0,64) chunk 256
        gemm_body64(mT, fcow, P2, NEMB, 256, id & 31, id >> 5);
        return;
    }
    id -= 2048;
    int bh = id >> 4, c = id & 15;
    int b = bh >> 4, h = bh & 15;

    __shared__ const float* kparr[CH];
    __shared__ const float* vparr[CH];
    __shared__ float sc[CH];

    // lane = one KV row: pointer setup with cache-override scan
    {
        int ks = kidx[b * KVLEN + c * CH + t];
        int vs = vidx[b * KVLEN + c * CH + t];
        const float* kbase = kcache + (size_t)ks * NEMB;
        const float* vbase = vcache + (size_t)vs * NEMB;
#pragma unroll
        for (int j = 0; j < BB; ++j) {
            if (nkl[j] == ks) kbase = knew + (size_t)j * NEMB;
            if (nvl[j] == vs) vbase = vnew + (size_t)j * NEMB;
        }
        kparr[t] = kbase + (size_t)h * DD;
        vparr[t] = vbase + (size_t)h * DD;
    }
    __syncthreads();

    int u = t & 15, g = t >> 4;    // 16-lane group; lane covers d = u*4 + j*64
    float4 qf[4];
#pragma unroll
    for (int j = 0; j < 4; ++j) qf[j] = *(const float4*)(q + (size_t)b * NEMB + (size_t)h * DD + u * 4 + j * 64);

    // QK: 4 rows at a time (one per group), 16 iterations covering 64 rows
#pragma unroll 4
    for (int it = 0; it < 16; ++it) {
        int l = it * 4 + g;
        const float* kr = kparr[l];
        float d = 0.f;
#pragma unroll
        for (int j = 0; j < 4; ++j) {
            float4 kf = *(const float4*)(kr + u * 4 + j * 64);
            d = fmaf(kf.x, qf[j].x, fmaf(kf.y, qf[j].y, fmaf(kf.z, qf[j].z, fmaf(kf.w, qf[j].w, d))));
        }
        d += __shfl_xor(d, 8, 64);
        d += __shfl_xor(d, 4, 64);
        d += __shfl_xor(d, 2, 64);
        d += __shfl_xor(d, 1, 64);
        if (u == 0) sc[l] = d * 0.0625f + mask[b * KVLEN + c * CH + l];
    }
    __syncthreads();

    // in-wave softmax over the 64 rows (row = lane)
    float sv = sc[t];
    float mx = sv;
#pragma unroll
    for (int o = 32; o > 0; o >>= 1) mx = fmaxf(mx, __shfl_xor(mx, o, 64));
    float e = expf(sv - mx);
    float sm = e;
#pragma unroll
    for (int o = 32; o > 0; o >>= 1) sm += __shfl_xor(sm, o, 64);

    // PV: lane owns d = t*4..t*4+3; V row pointer broadcast from LDS, weight from shfl
    float4 a4 = make_float4(0.f, 0.f, 0.f, 0.f);
#pragma unroll 8
    for (int l = 0; l < CH; ++l) {
        const float* vr = vparr[l];
        float4 vf = *(const float4*)(vr + t * 4);
        float pw = __shfl(e, l, 64);
        a4.x = fmaf(pw, vf.x, a4.x);
        a4.y = fmaf(pw, vf.y, a4.y);
        a4.z = fmaf(pw, vf.z, a4.z);
        a4.w = fmaf(pw, vf.w, a4.w);
    }

    int pi = bh * NCH + c;
    *(float4*)(pctx + (size_t)pi * DD + t * 4) = a4;
    if (t == 0) { pm[pi] = mx; pl[pi] = sm; }
}

// ---- phase 5: attention combine (512 blocks) ----
__global__ __launch_bounds__(256) void attn_comb_kernel(const float* __restrict__ pm,
    const float* __restrict__ pl, const float* __restrict__ pctx,
    float* __restrict__ ctxT)
{
    int bh = blockIdx.x;
    int b = bh >> 4, h = bh & 15;
    int t = threadIdx.x;
    float M = -INFINITY;
#pragma unroll
    for (int c = 0; c < NCH; ++c) M = fmaxf(M, pm[bh * NCH + c]);
    float L = 0.f, acc = 0.f;
#pragma unroll
    for (int c = 0; c < NCH; ++c) {
        float wv = expf(pm[bh * NCH + c] - M);
        L += pl[bh * NCH + c] * wv;
        acc += pctx[((size_t)bh * NCH + c) * DD + t] * wv;
    }
    ctxT[((size_t)h * DD + t) * BB + b] = acc / L;
}

// ---- phase 6: Wo gemm (512 blocks) + fc_out reduce -> mlp_tmp (512 blocks) ----
__global__ __launch_bounds__(256) void phase6_kernel(const float* __restrict__ ctxT,
    const float* __restrict__ wo, float* __restrict__ P0,
    const float* __restrict__ P2, const float* __restrict__ fcob,
    const float* __restrict__ resid, float* __restrict__ mlp_tmp)
{
    int id = blockIdx.x, t = threadIdx.x;
    if (id < 512) {
        gemm_body(ctxT, wo, P0, NEMB, 64, id & 7, id >> 3);
    } else {
        int j = id - 512;
        int m = j >> 4;
        int n = (j & 15) * 256 + t;
        const float* p = P2 + (size_t)m * NEMB + n;
        float s = 0.f;
#pragma unroll 4
        for (int i = 0; i < 64; ++i) { s += *p; p += (size_t)32 * NEMB; }
        mlp_tmp[(size_t)m * NEMB + n] = s + fcob[n] + resid[(size_t)m * NEMB + n];
    }
}

// ---- phase 7: Wo reduce + mlp_tmp -> out (512 blocks) ----
__global__ __launch_bounds__(256) void phase7_kernel(const float* __restrict__ P0,
    const float* __restrict__ mlp_tmp, float* __restrict__ out)
{
    int n = blockIdx.x * 256 + threadIdx.x;
    int m = blockIdx.y;
    const float* p = P0 + (size_t)m * NEMB + n;
    float s = 0.f;
#pragma unroll 4
    for (int i = 0; i < 64; ++i) { s += *p; p += (size_t)32 * NEMB; }
    out[(size_t)m * NEMB + n] = s + mlp_tmp[(size_t)m * NEMB + n];
}

extern "C" void kernel_launch(void* const* d_in, const int* in_sizes, int n_in,
                              void* d_out, int out_size, void* d_ws, size_t ws_size,
                              hipStream_t stream)
{
    (void)in_sizes; (void)n_in; (void)out_size; (void)ws_size;
    const float* hs      = (const float*)d_in[0];
    const float* kcache  = (const float*)d_in[1];
    const float* vcache  = (const float*)d_in[2];
    const float* ln_w    = (const float*)d_in[3];
    const float* ln_b    = (const float*)d_in[4];
    const float* wq      = (const float*)d_in[5];
    const float* wk      = (const float*)d_in[6];
    const float* wv      = (const float*)d_in[7];
    const float* wo      = (const float*)d_in[8];
    const float* fc_in_w = (const float*)d_in[9];
    const float* fc_in_b = (const float*)d_in[10];
    const float* fc_out_w= (const float*)d_in[11];
    const float* fc_out_b= (const float*)d_in[12];
    const float* mask    = (const float*)d_in[13];
    const int* nkl       = (const int*)d_in[14];
    const int* nvl       = (const int*)d_in[15];
    const int* kidx      = (const int*)d_in[16];
    const int* vidx      = (const int*)d_in[17];
    const int* pos       = (const int*)d_in[18];
    float* out = (float*)d_out;

    char* ws = (char*)d_ws;
    float* hT      = (float*)ws; ws += (size_t)NEMB * BB * 4;
    float* qb      = (float*)ws; ws += (size_t)BB * NEMB * 4;
    float* kb      = (float*)ws; ws += (size_t)BB * NEMB * 4;
    float* vb      = (float*)ws; ws += (size_t)BB * NEMB * 4;
    float* ctxT    = (float*)ws; ws += (size_t)NEMB * BB * 4;
    float* mlp_tmp = (float*)ws; ws += (size_t)BB * NEMB * 4;
    float* mT      = (float*)ws; ws += (size_t)NINT * BB * 4;
    float* pm      = (float*)ws; ws += (size_t)BB * HH * NCH * 4;
    float* pl      = (float*)ws; ws += (size_t)BB * HH * NCH * 4;
    float* pctx    = (float*)ws; ws += (size_t)BB * HH * NCH * DD * 4;
    float* Pq      = (float*)ws; ws += (size_t)3 * 32 * 32 * NEMB * 4;   // 50.3 MB
    float* P0      = (float*)ws; ws += (size_t)64 * 32 * NEMB * 4;       // 33.6 MB
    float* P1      = (float*)ws; ws += (size_t)16 * 32 * NINT * 4;       // 33.6 MB
    float* P2      = (float*)ws;                                          // 33.6 MB

    ln_kernel<<<BB, 256, 0, stream>>>(hs, ln_w, ln_b, hT);

    phase2_kernel<<<1280, 256, 0, stream>>>(hT, wq, wk, wv, Pq, fc_in_w, P1);

    phase3_kernel<<<2816, 256, 0, stream>>>(Pq, qb, kb, vb, pos, P1, fc_in_b, mT);

    phase4_kernel<<<10240, 64, 0, stream>>>(qb, kb, vb, kcache, vcache,
                                            kidx, vidx, nkl, nvl, mask,
                                            pm, pl, pctx, mT, fc_out_w, P2);

    attn_comb_kernel<<<BB * HH, 256, 0, stream>>>(pm, pl, pctx, ctxT);

    phase6_kernel<<<1024, 256, 0, stream>>>(ctxT, wo, P0, P2, fc_out_b, hs, mlp_tmp);

    phase7_kernel<<<dim3(16, 32), 256, 0, stream>>>(P0, mlp_tmp, out);
}